// Round 1
// 478.249 us; speedup vs baseline: 1.0387x; 1.0387x over previous
//
#include <hip/hip_runtime.h>
#include <hip/hip_bf16.h>
#include <cmath>

// Problem constants: B=64, N=256, IN=128, E=256, H=8, F=1024
#define BB 64
#define NNODES 256
#define INF_ 128
#define EE 256
#define HH 8
#define FFN 1024
#define BNROWS 16384   // B*N

typedef __attribute__((ext_vector_type(8))) short short8;
typedef __attribute__((ext_vector_type(4))) float floatx4;
typedef __attribute__((ext_vector_type(4))) unsigned short ushort4v;

__device__ __forceinline__ float b2f(unsigned short u) {
  union { unsigned u32; float f; } w; w.u32 = ((unsigned)u) << 16; return w.f;
}
__device__ __forceinline__ unsigned short f2b(float f) {
  union { float f; unsigned u32; } w; w.f = f;
  unsigned r = w.u32 + 0x7FFFu + ((w.u32 >> 16) & 1u);   // RNE
  return (unsigned short)(r >> 16);
}
// tanh-gelu (max abs dev from exact erf-gelu ~3e-4, far below bf16 rounding)
__device__ __forceinline__ float gelu_f(float x) {
  const float z = 0.7978845608028654f * (x + 0.044715f * x * x * x);
  const float e = __expf(2.0f * z);
  const float th = (e - 1.0f) / (e + 1.0f);
  return 0.5f * x * (1.0f + th);
}

typedef const __attribute__((address_space(1))) void GV;
typedef __attribute__((address_space(3))) void LV;

// async global->LDS: per-lane 16B source, wave-uniform LDS base (+lane*16)
__device__ __forceinline__ void gl_lds16(const unsigned short* g,
                                         unsigned short* l, int lane) {
#if __has_builtin(__builtin_amdgcn_global_load_lds)
  __builtin_amdgcn_global_load_lds((GV*)g, (LV*)l, 16, 0, 0);
#else
  *(short8*)(l + lane * 8) = *(const short8*)g;
#endif
}

// ---------------------------------------------------------------------------
// One kernel for ALL packing: transpose-cvt jobs + plain cvt jobs (C==0).
// ---------------------------------------------------------------------------
struct PackArgs {
  const float* src[12];
  unsigned short* dst[12];
  int R[12], C[12];
  int start[13];
};

__launch_bounds__(256)
__global__ void pack_kernel(PackArgs a)
{
  __shared__ float tile[32][33];
  const int bid = blockIdx.x;
  int j = 0;
  while (bid >= a.start[j + 1]) j++;
  const int lb = bid - a.start[j];
  const float* src = a.src[j];
  unsigned short* dst = a.dst[j];
  const int R = a.R[j], C = a.C[j];

  if (C == 0) {      // plain cvt, R = element count
    const int i = (lb * 256 + threadIdx.x) * 4;
    if (i >= R) return;
    floatx4 v = *(const floatx4*)(src + i);
    ushort4v o;
    #pragma unroll
    for (int k = 0; k < 4; k++) o[k] = f2b(v[k]);
    *(ushort4v*)(dst + i) = o;
    return;
  }
  const int tpr = C >> 5;
  const int c0 = (lb % tpr) * 32, r0 = (lb / tpr) * 32;
  const int tx = threadIdx.x & 31, ty = threadIdx.x >> 5;
  #pragma unroll
  for (int i = ty; i < 32; i += 8)
    tile[i][tx] = src[(long long)(r0 + i) * C + c0 + tx];
  __syncthreads();
  #pragma unroll
  for (int i = ty; i < 32; i += 8)
    dst[(long long)(c0 + i) * R + r0 + tx] = f2b(tile[tx][i]);
}

// ---------------------------------------------------------------------------
// dis = rsqrt(clip(rowsum(A),1,inf)); A = adj (f32) with diag forced to 1
// ---------------------------------------------------------------------------
__global__ void deg_kernel(const float* __restrict__ adj,
                           float* __restrict__ dis)
{
  const int g = blockIdx.x * 4 + (threadIdx.x >> 6);
  const int lane = threadIdx.x & 63;
  const int i = g & 255;
  floatx4 v = *(const floatx4*)(adj + (long long)g * 256 + lane * 4);
  float s = 0.f;
  #pragma unroll
  for (int jj = 0; jj < 4; jj++) {
    const int j = lane * 4 + jj;
    s += (j == i) ? 1.0f : v[jj];
  }
  #pragma unroll
  for (int off = 32; off > 0; off >>= 1) s += __shfl_xor(s, off);
  if (lane == 0) dis[g] = 1.0f / sqrtf(fmaxf(s, 1.0f));
}

// An[b,i,j] = bf16(dis_i * A_ij * dis_j)
__global__ void an_kernel(const float* __restrict__ adj,
                          const float* __restrict__ dis,
                          unsigned short* __restrict__ An)
{
  const long long base = ((long long)blockIdx.x * 256 + threadIdx.x) * 4;
  const int rowg = (int)(base >> 8);
  const int i = rowg & 255;
  const int brow = rowg & ~255;
  const int j0 = (int)(base & 255);
  const float di = dis[rowg];
  floatx4 v = *(const floatx4*)(adj + base);
  ushort4v o;
  #pragma unroll
  for (int jj = 0; jj < 4; jj++) {
    const int j = j0 + jj;
    const float a = (j == i) ? 1.0f : v[jj];
    o[jj] = f2b(di * dis[brow + j] * a);
  }
  *(ushort4v*)(An + base) = o;
}

// ---------------------------------------------------------------------------
// Batched bf16 MFMA GEMM, tile 128x128, BK=128 chunks, 512 threads (8 waves,
// 2x4), each wave 64x32 (acc[4][2]). A (M,K) rm; B (N,K) rm (always NT).
// LDS rows x 16 slots of 16B; slot s holds k-octet q = s ^ (r&7) (XOR swizzle).
// modes:
//  0: f32 store | 1: bf16 store | 2: f32 accumulate | 3: bf16 gelu(val+aux1[col])
//  5: TT store: b=row>>8,n=row&255 -> bf16 C[b*65536+col*256+n]
//  8: final:  f32 C[row*256+col] = gcn[i]+attf[i]+(val+aux1[col])*mask[row]
//  9: GCN epi (C'=U^T): token=zb*256+col, feat=row; g=relu((val+aux1[feat])*mask[token]);
//     bf16 C[token*256+feat]=g; gcn[...] (flag? += : =) g
// 12: f32 C[row*256+col] = gcn[idx] + (val + aux1[col]) * mask[row]
// 13: bf16 store of val * 0.0625  (ABH with attention scale folded)
// 15: Q'/V combined: col<2048 -> bf16 C[row*2048+col] (Q');
//     else V^T scatter: z2=(row>>8)*8+((col>>8)-8); bf16
//     aux2[z2*65536+(col&255)*256+(row&255)]
// ---------------------------------------------------------------------------
__launch_bounds__(512, 4)
__global__ void gemm_kernel(const unsigned short* __restrict__ A, int lda,
                            long long sAo, long long sAi,
                            const unsigned short* __restrict__ Bm, int ldb,
                            long long sBo, long long sBi,
                            void* __restrict__ Cv, int ldc,
                            long long sCo, long long sCi,
                            int K, int zshift, int mode, int flag,
                            const float* __restrict__ aux1,
                            const float* __restrict__ mask,
                            float* __restrict__ gcn,
                            void* __restrict__ aux2)
{
  __shared__ __align__(16) unsigned short sA[16384];   // 32KB
  __shared__ __align__(16) unsigned short sB[16384];   // 32KB

  const int t = threadIdx.x;
  const int z = blockIdx.z;
  const int zi = z & ((1 << zshift) - 1);
  const int zb = z >> zshift;
  const int m0 = blockIdx.x * 128;
  const int n0 = blockIdx.y * 128;
  A  += zb * sAo + zi * sAi;
  Bm += zb * sBo + zi * sBi;
  const long long cbase = zb * sCo + zi * sCi;

  const int lane = t & 63;
  const int w = t >> 6;              // wave 0..7
  const int wm = w >> 2, wn = w & 3; // 2 x 4
  const int lm = lane & 15, qd = lane >> 4;

  floatx4 acc[4][2] = {};

  const int sub = lane >> 4;        // 0..3
  const int qs  = lane & 15;        // slot within row
  const unsigned short* pA[4];
  const unsigned short* pB[4];
  #pragma unroll
  for (int i = 0; i < 4; i++) {
    const int d = w * 4 + i;        // DMA index 0..31
    const int r = d * 4 + sub;      // tile row 0..127
    const int co = (qs ^ (r & 7)) * 8;   // swizzled col octet (elements)
    pA[i] = A + (long long)(m0 + r) * lda + co;
    pB[i] = Bm + (long long)(n0 + r) * ldb + co;
  }

  for (int kk = 0; kk < K; kk += 128) {
    #pragma unroll
    for (int i = 0; i < 4; i++) {
      gl_lds16(pA[i] + kk, &sA[(w * 4 + i) * 512], lane);
      gl_lds16(pB[i] + kk, &sB[(w * 4 + i) * 512], lane);
    }
    __syncthreads();

    #pragma unroll
    for (int ks = 0; ks < 4; ks++) {
      short8 af[4], bg[2];
      const int q = ks * 4 + qd;          // k-octet 0..15
      #pragma unroll
      for (int mi = 0; mi < 4; mi++) {
        const int r = wm * 64 + mi * 16 + lm;
        af[mi] = *(const short8*)&sA[r * 128 + ((q ^ (r & 7)) * 8)];
      }
      #pragma unroll
      for (int ni = 0; ni < 2; ni++) {
        const int r = wn * 32 + ni * 16 + lm;
        bg[ni] = *(const short8*)&sB[r * 128 + ((q ^ (r & 7)) * 8)];
      }
      #pragma unroll
      for (int mi = 0; mi < 4; mi++)
        #pragma unroll
        for (int ni = 0; ni < 2; ni++)
          acc[mi][ni] = __builtin_amdgcn_mfma_f32_16x16x32_bf16(
              af[mi], bg[ni], acc[mi][ni], 0, 0, 0);
    }
    __syncthreads();
  }

  // ---- epilogue ----
  #pragma unroll
  for (int mi = 0; mi < 4; mi++) {
    const int row0 = m0 + wm * 64 + mi * 16 + qd * 4;
    #pragma unroll
    for (int ni = 0; ni < 2; ni++) {
      const int col = n0 + wn * 32 + ni * 16 + lm;
      floatx4 a = acc[mi][ni];
      if (mode == 0) {
        float* Cf = (float*)Cv;
        #pragma unroll
        for (int r = 0; r < 4; r++)
          Cf[cbase + (long long)(row0 + r) * ldc + col] = a[r];
      } else if (mode == 1) {
        unsigned short* Cb = (unsigned short*)Cv;
        #pragma unroll
        for (int r = 0; r < 4; r++)
          Cb[cbase + (long long)(row0 + r) * ldc + col] = f2b(a[r]);
      } else if (mode == 2) {
        float* Cf = (float*)Cv;
        #pragma unroll
        for (int r = 0; r < 4; r++)
          Cf[cbase + (long long)(row0 + r) * ldc + col] += a[r];
      } else if (mode == 3) {
        unsigned short* Cb = (unsigned short*)Cv;
        const float bv = aux1[col];
        #pragma unroll
        for (int r = 0; r < 4; r++)
          Cb[cbase + (long long)(row0 + r) * ldc + col] = f2b(gelu_f(a[r] + bv));
      } else if (mode == 5) {
        const int b = row0 >> 8, n = row0 & 255;
        ushort4v o;
        #pragma unroll
        for (int r = 0; r < 4; r++) o[r] = f2b(a[r]);
        *(ushort4v*)((unsigned short*)Cv + (long long)b * 65536 + col * 256 + n) = o;
      } else if (mode == 8) {
        float* Cf = (float*)Cv;
        const float* attf = (const float*)aux2;
        const float bv = aux1[col];
        #pragma unroll
        for (int r = 0; r < 4; r++) {
          const long long idx = (long long)(row0 + r) * 256 + col;
          Cf[idx] = gcn[idx] + attf[idx] + (a[r] + bv) * mask[row0 + r];
        }
      } else if (mode == 9) {
        const int token = zb * 256 + col;
        const float m = mask[token];
        ushort4v o; floatx4 g;
        #pragma unroll
        for (int r = 0; r < 4; r++) {
          const float v = fmaxf((a[r] + aux1[row0 + r]) * m, 0.f);
          o[r] = f2b(v); g[r] = v;
        }
        *(ushort4v*)((unsigned short*)Cv + (long long)token * 256 + row0) = o;
        float* gp = gcn + (long long)token * 256 + row0;
        if (flag) { floatx4 old = *(const floatx4*)gp; g += old; }
        *(floatx4*)gp = g;
      } else if (mode == 12) { // U = GCN + (val + bo)*mask
        float* Cf = (float*)Cv;
        const float bv = aux1[col];
        #pragma unroll
        for (int r = 0; r < 4; r++) {
          const long long idx = (long long)(row0 + r) * 256 + col;
          Cf[idx] = gcn[idx] + (a[r] + bv) * mask[row0 + r];
        }
      } else if (mode == 13) { // scaled bf16 (ABH /16)
        unsigned short* Cb = (unsigned short*)Cv;
        #pragma unroll
        for (int r = 0; r < 4; r++)
          Cb[cbase + (long long)(row0 + r) * ldc + col] = f2b(a[r] * 0.0625f);
      } else { // 15: Q' store / V^T scatter
        if (col < 2048) {
          unsigned short* Cb = (unsigned short*)Cv;
          #pragma unroll
          for (int r = 0; r < 4; r++)
            Cb[(long long)(row0 + r) * 2048 + col] = f2b(a[r]);
        } else {
          const int z2 = (row0 >> 8) * 8 + ((col >> 8) - 8);
          const int e = col & 255, n = row0 & 255;
          ushort4v o;
          #pragma unroll
          for (int r = 0; r < 4; r++) o[r] = f2b(a[r]);
          *(ushort4v*)((unsigned short*)aux2 + (long long)z2 * 65536 + e * 256 + n) = o;
        }
      }
    }
  }
}

// ---------------------------------------------------------------------------
// Fused attention v7 (latency-hiding restructure):
//  * whole Q' tile (128x256) staged once; its MFMA A-fragments are then held
//    in 64 VGPRs (afq[2][8]) for the entire S phase -> S-phase LDS reads halve
//    and Q' is never restaged.
//  * S phase is key-chunked (4 x 64 keys, full e=256 contraction per chunk)
//    with DOUBLE-BUFFERED H streaming: stage(c+1) is issued before compute(c)
//    (2-phase pipeline), so load latency hides under MFMA instead of being
//    drained at a bare barrier.  PV identical with V^T chunks.
//  * 130KB LDS -> 1 block/CU (in-block pipelining replaces cross-block TLP).
//  * grid swizzle co-locates the 8 h-blocks of one (b,mt) on one XCD so H_b
//    (128KB) and the dist tile (64KB) are fetched once per XCD group instead
//    of 8x from HBM.
// ---------------------------------------------------------------------------
__launch_bounds__(512, 2)
__global__ void attn_kernel(unsigned short* __restrict__ QP,   // (16384,2048) Q' in / Y out
                            const unsigned short* __restrict__ HBF, // (16384,256)
                            const unsigned short* __restrict__ VT,  // (512,256,256)
                            const unsigned short* __restrict__ DSTB,// (64,256,256) bf16
                            const float* __restrict__ mask)
{
  __shared__ __align__(16) unsigned short sP[32768];    // 64KB: Q' stage, then P
  __shared__ __align__(16) unsigned short sKV[32768];   // 64KB: 2 x 32KB stream bufs
  __shared__ float redm[2][128];
  __shared__ float reds[2][128];

  // h-octet XCD swizzle: blocks with equal (bi&7) share an XCD under the
  // round-robin dispatch; give each XCD whole (b,mt) groups (8 heads each).
  const int bi = blockIdx.x;              // 0..1023
  const int x = bi & 7, sdx = bi >> 3;
  const int h = sdx & 7;
  const int p = (sdx >> 3) * 8 + x;       // 0..127 : (b,mt) group id
  const int b = p >> 1, mt = p & 1;
  const int m0 = mt * 128;
  const int z = b * 8 + h;

  const int t = threadIdx.x, lane = t & 63, w = t >> 6;
  const int lm = lane & 15, qd = lane >> 4;
  const int wm4 = w >> 1, wn2 = w & 1;    // S phase: 4m x 2k waves
  const int wmP = w >> 2, wnP = w & 3;    // PV/epilogue: 2m x 4e waves

  unsigned short* Qm = QP + ((long long)(b * 256 + m0)) * 2048 + h * 256;
  const unsigned short* Hb = HBF + (long long)b * 65536;
  const unsigned short* Vb = VT + (long long)z * 65536;
  const unsigned short* db = DSTB + (long long)b * 65536;
  const float* maskb = mask + b * 256;

  const int rin2 = lane >> 5, qs32 = lane & 31;   // 512B-row staging (Q', H)
  const int rin8 = lane >> 3, qs8  = lane & 7;    // 128B-row staging (V^T)

  // ---- prologue: stage whole Q' tile (64KB) + H key-chunk 0 (32KB) ----
  #pragma unroll
  for (int i = 0; i < 8; i++) {
    const int d = w * 8 + i;              // 0..63, 2 rows each
    const int r = d * 2 + rin2;           // Q' row 0..127
    gl_lds16(Qm + (long long)r * 2048 + ((qs32 ^ (r & 7)) * 8), &sP[d * 512], lane);
  }
  #pragma unroll
  for (int i = 0; i < 4; i++) {
    const int d = w * 4 + i;              // 0..31
    const int r = d * 2 + rin2;           // key row 0..63
    gl_lds16(Hb + (long long)r * 256 + ((qs32 ^ (r & 7)) * 8), &sKV[d * 512], lane);
  }
  __syncthreads();

  // ---- Q' A-fragments -> registers (reused by all 4 key-chunks) ----
  short8 afq[2][8];
  #pragma unroll
  for (int mi = 0; mi < 2; mi++) {
    const int r = wm4 * 32 + mi * 16 + lm;
    #pragma unroll
    for (int ks = 0; ks < 8; ks++) {
      const int q = ks * 4 + qd;
      afq[mi][ks] = *(const short8*)&sP[r * 256 + ((q ^ (r & 7)) * 8)];
    }
  }

  // ---- S phase: 4 key-chunks of 64, H double-buffered ----
  floatx4 S[4][2][2] = {};
  #pragma unroll
  for (int c = 0; c < 4; c++) {
    const int cur = (c & 1) * 16384;
    if (c < 3) {                          // issue next chunk BEFORE compute
      #pragma unroll
      for (int i = 0; i < 4; i++) {
        const int d = w * 4 + i;
        const int r = d * 2 + rin2;
        gl_lds16(Hb + (long long)((c + 1) * 64 + r) * 256 + ((qs32 ^ (r & 7)) * 8),
                 &sKV[(cur ^ 16384) + d * 512], lane);
      }
    }
    #pragma unroll
    for (int ks = 0; ks < 8; ks++) {
      const int q = ks * 4 + qd;
      short8 bg[2];
      #pragma unroll
      for (int ni = 0; ni < 2; ni++) {
        const int kk = wn2 * 32 + ni * 16 + lm;
        bg[ni] = *(const short8*)&sKV[cur + kk * 256 + ((q ^ (kk & 7)) * 8)];
      }
      #pragma unroll
      for (int mi = 0; mi < 2; mi++)
        #pragma unroll
        for (int ni = 0; ni < 2; ni++)
          S[c][mi][ni] = __builtin_amdgcn_mfma_f32_16x16x32_bf16(
              afq[mi][ks], bg[ni], S[c][mi][ni], 0, 0, 0);
    }
    __syncthreads();
  }

  // ---- prefetch V^T chunk 0 into buf0 (softmax hides the latency) ----
  #pragma unroll
  for (int i = 0; i < 4; i++) {
    const int d = w * 4 + i;
    const int r = d * 8 + rin8;           // e-row 0..255
    gl_lds16(Vb + (long long)r * 256 + ((qs8 ^ (r & 7)) * 8), &sKV[d * 512], lane);
  }

  // ---- softmax over keys; dist is bf16 ----
  float mkv[4][2];
  #pragma unroll
  for (int c = 0; c < 4; c++)
    #pragma unroll
    for (int ni = 0; ni < 2; ni++)
      mkv[c][ni] = maskb[c * 64 + wn2 * 32 + ni * 16 + lm];

  float lred[2][4];
  #pragma unroll
  for (int mi = 0; mi < 2; mi++) {
    #pragma unroll
    for (int r = 0; r < 4; r++) {
      const int row = wm4 * 32 + mi * 16 + qd * 4 + r;
      const float mq = maskb[m0 + row];
      float mx = -3e38f;
      #pragma unroll
      for (int c = 0; c < 4; c++)
        #pragma unroll
        for (int ni = 0; ni < 2; ni++) {
          const int col = c * 64 + wn2 * 32 + ni * 16 + lm;
          const float dv = b2f(db[(long long)(m0 + row) * 256 + col]);
          const float v = (mq != 0.f && mkv[c][ni] != 0.f) ? (S[c][mi][ni][r] + dv) : -1e9f;
          S[c][mi][ni][r] = v;
          mx = fmaxf(mx, v);
        }
      lred[mi][r] = mx;
    }
  }
  #pragma unroll
  for (int off = 1; off < 16; off <<= 1)
    #pragma unroll
    for (int mi = 0; mi < 2; mi++)
      #pragma unroll
      for (int r = 0; r < 4; r++)
        lred[mi][r] = fmaxf(lred[mi][r], __shfl_xor(lred[mi][r], off));
  if (lm == 0)
    #pragma unroll
    for (int mi = 0; mi < 2; mi++)
      #pragma unroll
      for (int r = 0; r < 4; r++)
        redm[wn2][wm4 * 32 + mi * 16 + qd * 4 + r] = lred[mi][r];
  __syncthreads();

  #pragma unroll
  for (int mi = 0; mi < 2; mi++) {
    #pragma unroll
    for (int r = 0; r < 4; r++) {
      const int row = wm4 * 32 + mi * 16 + qd * 4 + r;
      const float gmax = fmaxf(redm[0][row], redm[1][row]);
      float ss = 0.f;
      #pragma unroll
      for (int c = 0; c < 4; c++)
        #pragma unroll
        for (int ni = 0; ni < 2; ni++) {
          const float e = __expf(S[c][mi][ni][r] - gmax);   // invalid -> exactly 0
          S[c][mi][ni][r] = e;
          ss += e;
        }
      lred[mi][r] = ss;
    }
  }
  #pragma unroll
  for (int off = 1; off < 16; off <<= 1)
    #pragma unroll
    for (int mi = 0; mi < 2; mi++)
      #pragma unroll
      for (int r = 0; r < 4; r++)
        lred[mi][r] += __shfl_xor(lred[mi][r], off);
  if (lm == 0)
    #pragma unroll
    for (int mi = 0; mi < 2; mi++)
      #pragma unroll
      for (int r = 0; r < 4; r++)
        reds[wn2][wm4 * 32 + mi * 16 + qd * 4 + r] = lred[mi][r];
  __syncthreads();

  // ---- normalize and write P (bf16, swizzled) into sP ----
  #pragma unroll
  for (int mi = 0; mi < 2; mi++)
    #pragma unroll
    for (int r = 0; r < 4; r++) {
      const int row = wm4 * 32 + mi * 16 + qd * 4 + r;
      const float inv = 1.0f / (reds[0][row] + reds[1][row]);
      #pragma unroll
      for (int c = 0; c < 4; c++)
        #pragma unroll
        for (int ni = 0; ni < 2; ni++) {
          const int col = c * 64 + wn2 * 32 + ni * 16 + lm;
          sP[row * 256 + (((col >> 3) ^ (row & 7)) * 8) + (col & 7)] =
              f2b(S[c][mi][ni][r] * inv);
        }
    }
  __syncthreads();                        // P visible; V0 drained

  // ---- PV phase: 4 key-chunks, V^T double-buffered ----
  floatx4 Y[4][4] = {};
  #pragma unroll
  for (int c = 0; c < 4; c++) {
    const int cur = (c & 1) * 16384;
    if (c < 3) {                          // issue next chunk BEFORE compute
      #pragma unroll
      for (int i = 0; i < 4; i++) {
        const int d = w * 4 + i;
        const int r = d * 8 + rin8;
        gl_lds16(Vb + (long long)r * 256 + (c + 1) * 64 + ((qs8 ^ (r & 7)) * 8),
                 &sKV[(cur ^ 16384) + d * 512], lane);
      }
    }
    #pragma unroll
    for (int ks = 0; ks < 2; ks++) {
      const int o = ks * 4 + qd;          // octet within chunk (0..7)
      const int qP = c * 8 + o;           // octet within P row (0..31)
      short8 af[4], bg[4];
      #pragma unroll
      for (int mi = 0; mi < 4; mi++) {
        const int r = wmP * 64 + mi * 16 + lm;
        af[mi] = *(const short8*)&sP[r * 256 + ((qP ^ (r & 7)) * 8)];
      }
      #pragma unroll
      for (int ni = 0; ni < 4; ni++) {
        const int e = wnP * 64 + ni * 16 + lm;
        bg[ni] = *(const short8*)&sKV[cur + e * 64 + ((o ^ (e & 7)) * 8)];
      }
      #pragma unroll
      for (int mi = 0; mi < 4; mi++)
        #pragma unroll
        for (int ni = 0; ni < 4; ni++)
          Y[mi][ni] = __builtin_amdgcn_mfma_f32_16x16x32_bf16(
              af[mi], bg[ni], Y[mi][ni], 0, 0, 0);
    }
    __syncthreads();
  }

  // ---- epilogue: Y -> LDS (stride 264, two 64-row halves) -> 16B stores ----
  #pragma unroll
  for (int half = 0; half < 2; half++) {
    __syncthreads();
    if (wmP == half) {
      #pragma unroll
      for (int mi = 0; mi < 4; mi++)
        #pragma unroll
        for (int ni = 0; ni < 4; ni++) {
          const int col = wnP * 64 + ni * 16 + lm;
          #pragma unroll
          for (int r = 0; r < 4; r++) {
            const int rl = mi * 16 + qd * 4 + r;    // 0..63
            sKV[rl * 264 + col] = f2b(Y[mi][ni][r]);
          }
        }
    }
    __syncthreads();
    #pragma unroll
    for (int it = 0; it < 4; it++) {
      const int idx = it * 512 + t;        // 0..2047 = 64 rows x 32 x 16B
      const int row = idx >> 5, u = idx & 31;
      short8 v = *(const short8*)&sKV[row * 264 + u * 8];
      *(short8*)(Qm + (long long)(half * 64 + row) * 2048 + u * 8) = v;
    }
  }
}

// ---------------------------------------------------------------------------
__global__ void ln_kernel(const float* __restrict__ X,
                          const float* __restrict__ gam,
                          const float* __restrict__ bet,
                          unsigned short* __restrict__ out)
{
  const int g = blockIdx.x * 4 + (threadIdx.x >> 6);
  const int lane = threadIdx.x & 63;
  floatx4 v = *(const floatx4*)(X + (long long)g * 256 + lane * 4);
  float s = v[0] + v[1] + v[2] + v[3];
  float sq = v[0]*v[0] + v[1]*v[1] + v[2]*v[2] + v[3]*v[3];
  #pragma unroll
  for (int off = 32; off > 0; off >>= 1) {
    s  += __shfl_xor(s, off);
    sq += __shfl_xor(sq, off);
  }
  const float mean = s * (1.0f / 256.0f);
  const float var = sq * (1.0f / 256.0f) - mean * mean;
  const float rs = 1.0f / sqrtf(var + 1e-5f);
  ushort4v o;
  #pragma unroll
  for (int jj = 0; jj < 4; jj++) {
    const int c = lane * 4 + jj;
    o[jj] = f2b((v[jj] - mean) * rs * gam[c] + bet[c]);
  }
  *(ushort4v*)(out + (long long)g * 256 + lane * 4) = o;
}

// ---------------------------------------------------------------------------
static inline void launch_gemm(hipStream_t st, int M, int N, int batch,
    const void* A, int lda, long long sAo, long long sAi,
    const void* B, int ldb, long long sBo, long long sBi,
    void* C, int ldc, long long sCo, long long sCi,
    int K, int zshift, int mode, int flag,
    const float* aux1, const float* mask, float* gcn, void* aux2)
{
  dim3 grid(M / 128, N / 128, batch), blk(512);
  gemm_kernel<<<grid, blk, 0, st>>>(
      (const unsigned short*)A, lda, sAo, sAi,
      (const unsigned short*)B, ldb, sBo, sBi,
      C, ldc, sCo, sCi, K, zshift, mode, flag, aux1, mask, gcn, aux2);
}

extern "C" void kernel_launch(void* const* d_in, const int* in_sizes, int n_in,
                              void* d_out, int out_size, void* d_ws, size_t ws_size,
                              hipStream_t stream)
{
  (void)in_sizes; (void)n_in; (void)out_size;
  const float* x    = (const float*)d_in[0];
  const float* adj  = (const float*)d_in[1];
  const float* mask = (const float*)d_in[2];
  const float* dist = (const float*)d_in[3];
  const float* W1   = (const float*)d_in[4];
  const float* b1   = (const float*)d_in[5];
  const float* W2   = (const float*)d_in[6];
  const float* b2   = (const float*)d_in[7];
  const float* W3   = (const float*)d_in[8];
  const float* b3   = (const float*)d_in[9];
  const float* ln1g = (const float*)d_in[10];
  const float* ln1b = (const float*)d_in[11];
  const float* Wq   = (const float*)d_in[12];
  const float* Wk   = (const float*)d_in[13];
  const float* Wv   = (const float*)d_in[14];
  const float* Wo   = (const float*)d_in[15];
  const float* bo   = (const float*)d_in[16];
  const float* ln2g = (const float*)d_in[17];
  const float* ln2b = (const float*)d_in[18];
  const float* Wf1  = (const float*)d_in[19];
  const float* bf1  = (const float*)d_in[20];
  const float* Wf2  = (const float*)d_in[21];
  const float* bf2  = (const float*)d_in[22];

  char* w = (char*)d_ws;
  auto alloc = [&](size_t sz) { void* p = (void*)w; w += sz; return p; };
  // persistent (~61 MB)
  unsigned short* W1T   = (unsigned short*)alloc(65536);      // (256,128)
  unsigned short* W2T   = (unsigned short*)alloc(131072);     // (256,256)
  unsigned short* W3T   = (unsigned short*)alloc(131072);
  unsigned short* ABH   = (unsigned short*)alloc(1048576);    // (2048,256) = Wk_h Wq_h^T /16
  unsigned short* WVT   = (unsigned short*)alloc(1048576);    // (2048,256)
  unsigned short* WOT   = (unsigned short*)alloc(1048576);    // (256,2048)
  unsigned short* WF1T  = (unsigned short*)alloc(524288);     // (1024,256)
  unsigned short* WF2T  = (unsigned short*)alloc(524288);     // (256,1024)
  unsigned short* WQb   = (unsigned short*)alloc(1048576);    // (256,2048) plain
  unsigned short* WKb   = (unsigned short*)alloc(1048576);    // (256,2048) plain
  unsigned short* XBF   = (unsigned short*)alloc(4194304);    // (16384,128)
  unsigned short* DSTB  = (unsigned short*)alloc(8388608);    // (64,256,256) bf16 dist
  float*          GCN   = (float*)         alloc(16777216);   // (16384,256)
  float*          U     = (float*)         alloc(16777216);   // ATT f32
  unsigned short* HBF   = (unsigned short*)alloc(8388608);    // (16384,256)
  float*          DIS   = (float*)         alloc(65536);
  // scratch union (peak = attention: 134.2 MB)
  char* scratch = (char*)alloc(134217728);
  if ((size_t)(w - (char*)d_ws) > ws_size) return;
  // gcn phase views
  unsigned short* AN  = (unsigned short*)scratch;              // 8.4 MB
  unsigned short* TT  = (unsigned short*)(scratch + 8388608);  // 8.4 MB
  unsigned short* GBF = (unsigned short*)(scratch + 16777216); // 8.4 MB
  // attention phase views
  unsigned short* QPB = (unsigned short*)scratch;                 // (16384,2048) 67 MB  Q'->Y
  unsigned short* VT  = (unsigned short*)(scratch + 67108864);    // (512,256,256) 67 MB
  // ffn phase view
  unsigned short* FFB = (unsigned short*)scratch;                 // 33.6 MB

  // ---- single packing launch: 7 transposes + 4 plain cvts ----
  PackArgs pa;
  const float* srcs[11] = {W1, W2, W3, Wv, Wo, Wf1, Wf2, x, Wq, Wk, dist};
  unsigned short* dsts[11] = {W1T, W2T, W3T, WVT, WOT, WF1T, WF2T, XBF, WQb, WKb, DSTB};
  const int Rs[11] = {128, 256, 256, 256, 2048, 256, 1024,
                      BNROWS * INF_, EE * HH * EE, EE * HH * EE, BB * 65536};
  const int Cs[11] = {256, 256, 256, 2048, 256, 1024, 256, 0, 0, 0, 0};
  const int sts[12] = {0, 32, 96, 160, 672, 1184, 1440, 1696, 3744, 4256, 4768, 8864};
  for (int j = 0; j < 11; j++) {
    pa.src[j] = srcs[j]; pa.dst[j] = dsts[j]; pa.R[j] = Rs[j]; pa.C[j] = Cs[j];
  }
  for (int j = 0; j < 12; j++) pa.start[j] = sts[j];
  pack_kernel<<<8864, 256, 0, stream>>>(pa);

  // ---- adjacency normalization ----
  deg_kernel<<<4096, 256, 0, stream>>>(adj, DIS);
  an_kernel<<<4096, 256, 0, stream>>>(adj, DIS, AN);

  // ---- ABH_h = Wk_h Wq_h^T / 16  (8 heads, tiny batched GEMM) ----
  launch_gemm(stream, 256, 256, 8, WKb, 2048, 256, 0, WQb, 2048, 256, 0,
              ABH, 256, 65536, 0, 256, 0, 13, 0, nullptr, nullptr, nullptr, nullptr);

  // ---- GCN stack ----
  launch_gemm(stream, BNROWS, EE, 1, XBF, 128, 0,0, W1T, 128, 0,0,
              TT, 256, 0,0, 128, 0, 5, 0, nullptr, nullptr, nullptr, nullptr);
  launch_gemm(stream, 256, 256, BB, TT, 256, 65536,0, AN, 256, 65536,0,
              GBF, 256, 0,0, 256, 0, 9, 0, b1, mask, GCN, nullptr);
  launch_gemm(stream, BNROWS, EE, 1, GBF, 256, 0,0, W2T, 256, 0,0,
              TT, 256, 0,0, 256, 0, 5, 0, nullptr, nullptr, nullptr, nullptr);
  launch_gemm(stream, 256, 256, BB, TT, 256, 65536,0, AN, 256, 65536,0,
              GBF, 256, 0,0, 256, 0, 9, 1, b2, mask, GCN, nullptr);
  launch_gemm(stream, BNROWS, EE, 1, GBF, 256, 0,0, W3T, 256, 0,0,
              TT, 256, 0,0, 256, 0, 5, 0, nullptr, nullptr, nullptr, nullptr);
  launch_gemm(stream, 256, 256, BB, TT, 256, 65536,0, AN, 256, 65536,0,
              GBF, 256, 0,0, 256, 0, 9, 1, b3, mask, GCN, nullptr);

  // ---- LN1 ----
  ln_kernel<<<4096, 256, 0, stream>>>(GCN, ln1g, ln1b, HBF);

  // ---- attention: combined Q'(=H·ABH^T)/V GEMM -> fused attn -> Y@Wo ----
  launch_gemm(stream, BNROWS, 4096, 1, HBF, 256, 0,0, ABH, 256, 0,0,
              QPB, 2048, 0,0, 256, 0, 15, 0, nullptr, nullptr, nullptr, VT);
  attn_kernel<<<1024, 512, 0, stream>>>(QPB, HBF, VT, DSTB, mask);
  launch_gemm(stream, BNROWS, EE, 1, QPB, 2048, 0,0, WOT, 2048, 0,0,
              U, 256, 0,0, 2048, 0, 12, 0, bo, mask, GCN, nullptr);

  // ---- LN2 + FFN (final residual fused into FFN2 epilogue) ----
  ln_kernel<<<4096, 256, 0, stream>>>(U, ln2g, ln2b, HBF);
  launch_gemm(stream, BNROWS, FFN, 1, HBF, 256, 0,0, WF1T, 256, 0,0,
              FFB, 1024, 0,0, 256, 0, 3, 0, bf1, nullptr, nullptr, nullptr);
  launch_gemm(stream, BNROWS, EE, 1, FFB, 1024, 0,0, WF2T, 1024, 0,0,
              d_out, 256, 0,0, 1024, 0, 8, 0, bf2, mask, GCN, U);
}

// Round 2
// 467.379 us; speedup vs baseline: 1.0628x; 1.0233x over previous
//
#include <hip/hip_runtime.h>
#include <hip/hip_bf16.h>
#include <cmath>

// Problem constants: B=64, N=256, IN=128, E=256, H=8, F=1024
#define BB 64
#define NNODES 256
#define INF_ 128
#define EE 256
#define HH 8
#define FFN 1024
#define BNROWS 16384   // B*N

typedef __attribute__((ext_vector_type(8))) short short8;
typedef __attribute__((ext_vector_type(4))) float floatx4;
typedef __attribute__((ext_vector_type(4))) unsigned short ushort4v;

__device__ __forceinline__ float b2f(unsigned short u) {
  union { unsigned u32; float f; } w; w.u32 = ((unsigned)u) << 16; return w.f;
}
__device__ __forceinline__ unsigned short f2b(float f) {
  union { float f; unsigned u32; } w; w.f = f;
  unsigned r = w.u32 + 0x7FFFu + ((w.u32 >> 16) & 1u);   // RNE
  return (unsigned short)(r >> 16);
}
// tanh-gelu (max abs dev from exact erf-gelu ~3e-4, far below bf16 rounding)
__device__ __forceinline__ float gelu_f(float x) {
  const float z = 0.7978845608028654f * (x + 0.044715f * x * x * x);
  const float e = __expf(2.0f * z);
  const float th = (e - 1.0f) / (e + 1.0f);
  return 0.5f * x * (1.0f + th);
}

typedef const __attribute__((address_space(1))) void GV;
typedef __attribute__((address_space(3))) void LV;

// async global->LDS: per-lane 16B source, wave-uniform LDS base (+lane*16)
__device__ __forceinline__ void gl_lds16(const unsigned short* g,
                                         unsigned short* l, int lane) {
#if __has_builtin(__builtin_amdgcn_global_load_lds)
  __builtin_amdgcn_global_load_lds((GV*)g, (LV*)l, 16, 0, 0);
#else
  *(short8*)(l + lane * 8) = *(const short8*)g;
#endif
}

// ---------------------------------------------------------------------------
// One kernel for ALL packing: transpose-cvt jobs + plain cvt jobs (C==0).
// ---------------------------------------------------------------------------
struct PackArgs {
  const float* src[12];
  unsigned short* dst[12];
  int R[12], C[12];
  int start[13];
};

__launch_bounds__(256)
__global__ void pack_kernel(PackArgs a)
{
  __shared__ float tile[32][33];
  const int bid = blockIdx.x;
  int j = 0;
  while (bid >= a.start[j + 1]) j++;
  const int lb = bid - a.start[j];
  const float* src = a.src[j];
  unsigned short* dst = a.dst[j];
  const int R = a.R[j], C = a.C[j];

  if (C == 0) {      // plain cvt, R = element count
    const int i = (lb * 256 + threadIdx.x) * 4;
    if (i >= R) return;
    floatx4 v = *(const floatx4*)(src + i);
    ushort4v o;
    #pragma unroll
    for (int k = 0; k < 4; k++) o[k] = f2b(v[k]);
    *(ushort4v*)(dst + i) = o;
    return;
  }
  const int tpr = C >> 5;
  const int c0 = (lb % tpr) * 32, r0 = (lb / tpr) * 32;
  const int tx = threadIdx.x & 31, ty = threadIdx.x >> 5;
  #pragma unroll
  for (int i = ty; i < 32; i += 8)
    tile[i][tx] = src[(long long)(r0 + i) * C + c0 + tx];
  __syncthreads();
  #pragma unroll
  for (int i = ty; i < 32; i += 8)
    dst[(long long)(c0 + i) * R + r0 + tx] = f2b(tile[tx][i]);
}

// ---------------------------------------------------------------------------
// dis = rsqrt(clip(rowsum(A),1,inf)); A = adj (f32) with diag forced to 1
// ---------------------------------------------------------------------------
__global__ void deg_kernel(const float* __restrict__ adj,
                           float* __restrict__ dis)
{
  const int g = blockIdx.x * 4 + (threadIdx.x >> 6);
  const int lane = threadIdx.x & 63;
  const int i = g & 255;
  floatx4 v = *(const floatx4*)(adj + (long long)g * 256 + lane * 4);
  float s = 0.f;
  #pragma unroll
  for (int jj = 0; jj < 4; jj++) {
    const int j = lane * 4 + jj;
    s += (j == i) ? 1.0f : v[jj];
  }
  #pragma unroll
  for (int off = 32; off > 0; off >>= 1) s += __shfl_xor(s, off);
  if (lane == 0) dis[g] = 1.0f / sqrtf(fmaxf(s, 1.0f));
}

// An[b,i,j] = bf16(dis_i * A_ij * dis_j)
__global__ void an_kernel(const float* __restrict__ adj,
                          const float* __restrict__ dis,
                          unsigned short* __restrict__ An)
{
  const long long base = ((long long)blockIdx.x * 256 + threadIdx.x) * 4;
  const int rowg = (int)(base >> 8);
  const int i = rowg & 255;
  const int brow = rowg & ~255;
  const int j0 = (int)(base & 255);
  const float di = dis[rowg];
  floatx4 v = *(const floatx4*)(adj + base);
  ushort4v o;
  #pragma unroll
  for (int jj = 0; jj < 4; jj++) {
    const int j = j0 + jj;
    const float a = (j == i) ? 1.0f : v[jj];
    o[jj] = f2b(di * dis[brow + j] * a);
  }
  *(ushort4v*)(An + base) = o;
}

// ---------------------------------------------------------------------------
// Batched bf16 MFMA GEMM, tile 128x128, BK=128 chunks, 512 threads (8 waves,
// 2x4), each wave 64x32 (acc[4][2]). A (M,K) rm; B (N,K) rm (always NT).
// LDS rows x 16 slots of 16B; slot s holds k-octet q = s ^ (r&7) (XOR swizzle).
// modes:
//  0: f32 store | 1: bf16 store | 2: f32 accumulate | 3: bf16 gelu(val+aux1[col])
//  5: TT store: b=row>>8,n=row&255 -> bf16 C[b*65536+col*256+n]
//  8: final:  f32 C[row*256+col] = gcn[i]+attf[i]+(val+aux1[col])*mask[row]
//  9: GCN epi (C'=U^T): token=zb*256+col, feat=row; g=relu((val+aux1[feat])*mask[token]);
//     bf16 C[token*256+feat]=g; gcn[...] (flag? += : =) g
// 12: f32 C[row*256+col] = gcn[idx] + (val + aux1[col]) * mask[row]
// 13: bf16 store of val * 0.0625  (ABH with attention scale folded)
// 15: Q'/V combined: col<2048 -> bf16 C[row*2048+col] (Q');
//     else V^T scatter: z2=(row>>8)*8+((col>>8)-8); bf16
//     aux2[z2*65536+(col&255)*256+(row&255)]
// ---------------------------------------------------------------------------
__launch_bounds__(512, 4)
__global__ void gemm_kernel(const unsigned short* __restrict__ A, int lda,
                            long long sAo, long long sAi,
                            const unsigned short* __restrict__ Bm, int ldb,
                            long long sBo, long long sBi,
                            void* __restrict__ Cv, int ldc,
                            long long sCo, long long sCi,
                            int K, int zshift, int mode, int flag,
                            const float* __restrict__ aux1,
                            const float* __restrict__ mask,
                            float* __restrict__ gcn,
                            void* __restrict__ aux2)
{
  __shared__ __align__(16) unsigned short sA[16384];   // 32KB
  __shared__ __align__(16) unsigned short sB[16384];   // 32KB

  const int t = threadIdx.x;
  const int z = blockIdx.z;
  const int zi = z & ((1 << zshift) - 1);
  const int zb = z >> zshift;
  const int m0 = blockIdx.x * 128;
  const int n0 = blockIdx.y * 128;
  A  += zb * sAo + zi * sAi;
  Bm += zb * sBo + zi * sBi;
  const long long cbase = zb * sCo + zi * sCi;

  const int lane = t & 63;
  const int w = t >> 6;              // wave 0..7
  const int wm = w >> 2, wn = w & 3; // 2 x 4
  const int lm = lane & 15, qd = lane >> 4;

  floatx4 acc[4][2] = {};

  const int sub = lane >> 4;        // 0..3
  const int qs  = lane & 15;        // slot within row
  const unsigned short* pA[4];
  const unsigned short* pB[4];
  #pragma unroll
  for (int i = 0; i < 4; i++) {
    const int d = w * 4 + i;        // DMA index 0..31
    const int r = d * 4 + sub;      // tile row 0..127
    const int co = (qs ^ (r & 7)) * 8;   // swizzled col octet (elements)
    pA[i] = A + (long long)(m0 + r) * lda + co;
    pB[i] = Bm + (long long)(n0 + r) * ldb + co;
  }

  for (int kk = 0; kk < K; kk += 128) {
    #pragma unroll
    for (int i = 0; i < 4; i++) {
      gl_lds16(pA[i] + kk, &sA[(w * 4 + i) * 512], lane);
      gl_lds16(pB[i] + kk, &sB[(w * 4 + i) * 512], lane);
    }
    __syncthreads();

    #pragma unroll
    for (int ks = 0; ks < 4; ks++) {
      short8 af[4], bg[2];
      const int q = ks * 4 + qd;          // k-octet 0..15
      #pragma unroll
      for (int mi = 0; mi < 4; mi++) {
        const int r = wm * 64 + mi * 16 + lm;
        af[mi] = *(const short8*)&sA[r * 128 + ((q ^ (r & 7)) * 8)];
      }
      #pragma unroll
      for (int ni = 0; ni < 2; ni++) {
        const int r = wn * 32 + ni * 16 + lm;
        bg[ni] = *(const short8*)&sB[r * 128 + ((q ^ (r & 7)) * 8)];
      }
      #pragma unroll
      for (int mi = 0; mi < 4; mi++)
        #pragma unroll
        for (int ni = 0; ni < 2; ni++)
          acc[mi][ni] = __builtin_amdgcn_mfma_f32_16x16x32_bf16(
              af[mi], bg[ni], acc[mi][ni], 0, 0, 0);
    }
    __syncthreads();
  }

  // ---- epilogue ----
  #pragma unroll
  for (int mi = 0; mi < 4; mi++) {
    const int row0 = m0 + wm * 64 + mi * 16 + qd * 4;
    #pragma unroll
    for (int ni = 0; ni < 2; ni++) {
      const int col = n0 + wn * 32 + ni * 16 + lm;
      floatx4 a = acc[mi][ni];
      if (mode == 0) {
        float* Cf = (float*)Cv;
        #pragma unroll
        for (int r = 0; r < 4; r++)
          Cf[cbase + (long long)(row0 + r) * ldc + col] = a[r];
      } else if (mode == 1) {
        unsigned short* Cb = (unsigned short*)Cv;
        #pragma unroll
        for (int r = 0; r < 4; r++)
          Cb[cbase + (long long)(row0 + r) * ldc + col] = f2b(a[r]);
      } else if (mode == 2) {
        float* Cf = (float*)Cv;
        #pragma unroll
        for (int r = 0; r < 4; r++)
          Cf[cbase + (long long)(row0 + r) * ldc + col] += a[r];
      } else if (mode == 3) {
        unsigned short* Cb = (unsigned short*)Cv;
        const float bv = aux1[col];
        #pragma unroll
        for (int r = 0; r < 4; r++)
          Cb[cbase + (long long)(row0 + r) * ldc + col] = f2b(gelu_f(a[r] + bv));
      } else if (mode == 5) {
        const int b = row0 >> 8, n = row0 & 255;
        ushort4v o;
        #pragma unroll
        for (int r = 0; r < 4; r++) o[r] = f2b(a[r]);
        *(ushort4v*)((unsigned short*)Cv + (long long)b * 65536 + col * 256 + n) = o;
      } else if (mode == 8) {
        float* Cf = (float*)Cv;
        const float* attf = (const float*)aux2;
        const float bv = aux1[col];
        #pragma unroll
        for (int r = 0; r < 4; r++) {
          const long long idx = (long long)(row0 + r) * 256 + col;
          Cf[idx] = gcn[idx] + attf[idx] + (a[r] + bv) * mask[row0 + r];
        }
      } else if (mode == 9) {
        const int token = zb * 256 + col;
        const float m = mask[token];
        ushort4v o; floatx4 g;
        #pragma unroll
        for (int r = 0; r < 4; r++) {
          const float v = fmaxf((a[r] + aux1[row0 + r]) * m, 0.f);
          o[r] = f2b(v); g[r] = v;
        }
        *(ushort4v*)((unsigned short*)Cv + (long long)token * 256 + row0) = o;
        float* gp = gcn + (long long)token * 256 + row0;
        if (flag) { floatx4 old = *(const floatx4*)gp; g += old; }
        *(floatx4*)gp = g;
      } else if (mode == 12) { // U = GCN + (val + bo)*mask
        float* Cf = (float*)Cv;
        const float bv = aux1[col];
        #pragma unroll
        for (int r = 0; r < 4; r++) {
          const long long idx = (long long)(row0 + r) * 256 + col;
          Cf[idx] = gcn[idx] + (a[r] + bv) * mask[row0 + r];
        }
      } else if (mode == 13) { // scaled bf16 (ABH /16)
        unsigned short* Cb = (unsigned short*)Cv;
        #pragma unroll
        for (int r = 0; r < 4; r++)
          Cb[cbase + (long long)(row0 + r) * ldc + col] = f2b(a[r] * 0.0625f);
      } else { // 15: Q' store / V^T scatter
        if (col < 2048) {
          unsigned short* Cb = (unsigned short*)Cv;
          #pragma unroll
          for (int r = 0; r < 4; r++)
            Cb[(long long)(row0 + r) * 2048 + col] = f2b(a[r]);
        } else {
          const int z2 = (row0 >> 8) * 8 + ((col >> 8) - 8);
          const int e = col & 255, n = row0 & 255;
          ushort4v o;
          #pragma unroll
          for (int r = 0; r < 4; r++) o[r] = f2b(a[r]);
          *(ushort4v*)((unsigned short*)aux2 + (long long)z2 * 65536 + e * 256 + n) = o;
        }
      }
    }
  }
}

// ---------------------------------------------------------------------------
// Fused attention v8 (occupancy restructure):
//  * 64-row Q-tiles (grid 2048 = 64b x 8h x 4mt); LDS ~68KB -> 2 blocks/CU,
//    __launch_bounds__(512,4) caps VGPR at 128 -> 16 waves/CU.  Cross-block
//    TLP (the sibling block) hides every stage drain; v7's 1-block/CU
//    in-block pipeline could not (Occupancy 21%, MfmaUtil 14%).
//  * dist folded into the MFMA C-in: S acc initialized from dist, loads
//    issued at kernel start (latency hidden under Q'/H staging).  Removes
//    the 64-scalar-load + add hot spot from softmax.
//  * P stored in per-chunk planes [4][64][64] (128B rows, v6's measured
//    0-conflict layout) instead of v7's 512B-row layout (3.67M conflicts).
//  * s_setprio(1) around MFMA clusters (pays off with 2 phase-diverse
//    blocks/CU).
// ---------------------------------------------------------------------------
__launch_bounds__(512, 4)
__global__ void attn_kernel(unsigned short* __restrict__ QP,   // (16384,2048) Q' in / Y out
                            const unsigned short* __restrict__ HBF, // (16384,256)
                            const unsigned short* __restrict__ VT,  // (512,256,256)
                            const unsigned short* __restrict__ DSTB,// (64,256,256) bf16
                            const float* __restrict__ mask)
{
  __shared__ __align__(16) unsigned short sP[16896];   // 33KB: Q' / P planes / Y epi (64x264)
  __shared__ __align__(16) unsigned short sKV[16384];  // 32KB: H/V chunk
  __shared__ float redm[4][64];
  __shared__ float reds[4][64];

  // XCD swizzle: the 8 h-blocks of one (b,mt) share an XCD (same bi&7 under
  // round-robin) so H_b and the dist tile are L2-deduped.
  const int bi = blockIdx.x;              // 0..2047
  const int x = bi & 7;
  const int h = (bi >> 3) & 7;
  const int p = (bi >> 6) * 8 + x;        // 0..255 : (b,mt) group id
  const int b = p >> 2, mt = p & 3;
  const int m0 = mt * 64;
  const int z = b * 8 + h;

  const int t = threadIdx.x, lane = t & 63, w = t >> 6;
  const int lm = lane & 15, qd = lane >> 4;
  const int wm2 = w >> 2, wn4 = w & 3;    // 2 row-groups x 4 key/e-groups

  unsigned short* Qm = QP + ((long long)(b * 256 + m0)) * 2048 + h * 256;
  const unsigned short* Hb = HBF + (long long)b * 65536;
  const unsigned short* Vb = VT + (long long)z * 65536;
  const unsigned short* db = DSTB + (long long)b * 65536 + (long long)m0 * 256;
  const float* maskb = mask + b * 256;

  const int rin2 = lane >> 5, qs32 = lane & 31;   // 512B-row staging (Q')
  const int rin8 = lane >> 3, qs8  = lane & 7;    // 128B-row staging (H/V)

  // ---- S acc initialized from dist (folds "+dist" into MFMA C-in); the 32
  //      scalar loads issue first so their latency hides under staging ----
  floatx4 S[2][4];
  #pragma unroll
  for (int mi = 0; mi < 2; mi++)
    #pragma unroll
    for (int ni = 0; ni < 4; ni++) {
      const int col = wn4 * 64 + ni * 16 + lm;
      #pragma unroll
      for (int r = 0; r < 4; r++) {
        const int row = wm2 * 32 + mi * 16 + qd * 4 + r;
        S[mi][ni][r] = b2f(db[row * 256 + col]);
      }
    }

  // ---- stage Q' tile (64x256, 32KB) + H e-chunk 0 (256x64, 32KB) ----
  #pragma unroll
  for (int i = 0; i < 4; i++) {
    const int d = w * 4 + i;              // 0..31, 2 rows each
    const int r = d * 2 + rin2;           // Q' row 0..63
    gl_lds16(Qm + (long long)r * 2048 + ((qs32 ^ (r & 7)) * 8), &sP[d * 512], lane);
  }
  #pragma unroll
  for (int i = 0; i < 4; i++) {
    const int d = w * 4 + i;              // 0..31, 8 key-rows each
    const int r = d * 8 + rin8;           // key 0..255
    gl_lds16(Hb + (long long)r * 256 + ((qs8 ^ (r & 7)) * 8), &sKV[d * 512], lane);
  }
  __syncthreads();

  // ---- S phase: 4 e-chunks of 64 (B = H[keys][e-slice]) ----
  for (int c = 0; c < 4; c++) {
    __builtin_amdgcn_s_setprio(1);
    #pragma unroll
    for (int ks = 0; ks < 2; ks++) {
      const int ol = ks * 4 + qd;         // octet within chunk (0..7)
      short8 af[2], bg[4];
      #pragma unroll
      for (int mi = 0; mi < 2; mi++) {
        const int r = wm2 * 32 + mi * 16 + lm;
        const int q = c * 8 + ol;         // octet within Q' row (0..31)
        af[mi] = *(const short8*)&sP[r * 256 + ((q ^ (r & 7)) * 8)];
      }
      #pragma unroll
      for (int ni = 0; ni < 4; ni++) {
        const int kk = wn4 * 64 + ni * 16 + lm;
        bg[ni] = *(const short8*)&sKV[kk * 64 + ((ol ^ (kk & 7)) * 8)];
      }
      #pragma unroll
      for (int mi = 0; mi < 2; mi++)
        #pragma unroll
        for (int ni = 0; ni < 4; ni++)
          S[mi][ni] = __builtin_amdgcn_mfma_f32_16x16x32_bf16(
              af[mi], bg[ni], S[mi][ni], 0, 0, 0);
    }
    __builtin_amdgcn_s_setprio(0);
    __syncthreads();
    if (c < 3) {
      #pragma unroll
      for (int i = 0; i < 4; i++) {
        const int d = w * 4 + i;
        const int r = d * 8 + rin8;
        gl_lds16(Hb + (long long)r * 256 + (c + 1) * 64 + ((qs8 ^ (r & 7)) * 8),
                 &sKV[d * 512], lane);
      }
      __syncthreads();
    }
  }

  // ---- issue V^T key-chunk 0 now; softmax + its barriers hide it ----
  #pragma unroll
  for (int i = 0; i < 4; i++) {
    const int d = w * 4 + i;
    const int r = d * 8 + rin8;           // e-row 0..255
    gl_lds16(Vb + (long long)r * 256 + ((qs8 ^ (r & 7)) * 8), &sKV[d * 512], lane);
  }

  // ---- softmax over keys (dist already inside S) ----
  float mkv[4];
  #pragma unroll
  for (int ni = 0; ni < 4; ni++) mkv[ni] = maskb[wn4 * 64 + ni * 16 + lm];

  float lred[2][4];
  #pragma unroll
  for (int mi = 0; mi < 2; mi++) {
    #pragma unroll
    for (int r = 0; r < 4; r++) {
      const int row = wm2 * 32 + mi * 16 + qd * 4 + r;
      const float mq = maskb[m0 + row];
      float mx = -3e38f;
      #pragma unroll
      for (int ni = 0; ni < 4; ni++) {
        const float v = (mq != 0.f && mkv[ni] != 0.f) ? S[mi][ni][r] : -1e9f;
        S[mi][ni][r] = v;
        mx = fmaxf(mx, v);
      }
      lred[mi][r] = mx;
    }
  }
  #pragma unroll
  for (int off = 1; off < 16; off <<= 1)
    #pragma unroll
    for (int mi = 0; mi < 2; mi++)
      #pragma unroll
      for (int r = 0; r < 4; r++)
        lred[mi][r] = fmaxf(lred[mi][r], __shfl_xor(lred[mi][r], off));
  if (lm == 0)
    #pragma unroll
    for (int mi = 0; mi < 2; mi++)
      #pragma unroll
      for (int r = 0; r < 4; r++)
        redm[wn4][wm2 * 32 + mi * 16 + qd * 4 + r] = lred[mi][r];
  __syncthreads();

  #pragma unroll
  for (int mi = 0; mi < 2; mi++) {
    #pragma unroll
    for (int r = 0; r < 4; r++) {
      const int row = wm2 * 32 + mi * 16 + qd * 4 + r;
      const float gmax = fmaxf(fmaxf(redm[0][row], redm[1][row]),
                               fmaxf(redm[2][row], redm[3][row]));
      float ss = 0.f;
      #pragma unroll
      for (int ni = 0; ni < 4; ni++) {
        const float e = __expf(S[mi][ni][r] - gmax);   // invalid -> exactly 0
        S[mi][ni][r] = e;
        ss += e;
      }
      lred[mi][r] = ss;
    }
  }
  #pragma unroll
  for (int off = 1; off < 16; off <<= 1)
    #pragma unroll
    for (int mi = 0; mi < 2; mi++)
      #pragma unroll
      for (int r = 0; r < 4; r++)
        lred[mi][r] += __shfl_xor(lred[mi][r], off);
  if (lm == 0)
    #pragma unroll
    for (int mi = 0; mi < 2; mi++)
      #pragma unroll
      for (int r = 0; r < 4; r++)
        reds[wn4][wm2 * 32 + mi * 16 + qd * 4 + r] = lred[mi][r];
  __syncthreads();

  // ---- normalize, write P planes [wn4][64 rows][64 keys] (128B rows) ----
  #pragma unroll
  for (int mi = 0; mi < 2; mi++)
    #pragma unroll
    for (int r = 0; r < 4; r++) {
      const int row = wm2 * 32 + mi * 16 + qd * 4 + r;
      const float inv = 1.0f / (reds[0][row] + reds[1][row] +
                                reds[2][row] + reds[3][row]);
      #pragma unroll
      for (int ni = 0; ni < 4; ni++) {
        const int kl = ni * 16 + lm;                    // key within plane
        const int slot = (kl >> 3) ^ (row & 7);
        sP[wn4 * 4096 + row * 64 + slot * 8 + (kl & 7)] =
            f2b(S[mi][ni][r] * inv);
      }
    }
  __syncthreads();                        // P visible; V0 drained

  // ---- PV phase: 4 key-chunks (A = P plane c, B = V^T[e][key-slice]) ----
  floatx4 Y[2][4] = {};
  for (int c = 0; c < 4; c++) {
    __builtin_amdgcn_s_setprio(1);
    #pragma unroll
    for (int ks = 0; ks < 2; ks++) {
      const int ol = ks * 4 + qd;         // key-octet within chunk (0..7)
      short8 af[2], bg[4];
      #pragma unroll
      for (int mi = 0; mi < 2; mi++) {
        const int r = wm2 * 32 + mi * 16 + lm;
        af[mi] = *(const short8*)&sP[c * 4096 + r * 64 + ((ol ^ (r & 7)) * 8)];
      }
      #pragma unroll
      for (int ni = 0; ni < 4; ni++) {
        const int ee = wn4 * 64 + ni * 16 + lm;
        bg[ni] = *(const short8*)&sKV[ee * 64 + ((ol ^ (ee & 7)) * 8)];
      }
      #pragma unroll
      for (int mi = 0; mi < 2; mi++)
        #pragma unroll
        for (int ni = 0; ni < 4; ni++)
          Y[mi][ni] = __builtin_amdgcn_mfma_f32_16x16x32_bf16(
              af[mi], bg[ni], Y[mi][ni], 0, 0, 0);
    }
    __builtin_amdgcn_s_setprio(0);
    __syncthreads();
    if (c < 3) {
      #pragma unroll
      for (int i = 0; i < 4; i++) {
        const int d = w * 4 + i;
        const int r = d * 8 + rin8;
        gl_lds16(Vb + (long long)r * 256 + (c + 1) * 64 + ((qs8 ^ (r & 7)) * 8),
                 &sKV[d * 512], lane);
      }
      __syncthreads();
    }
  }

  // ---- epilogue: Y -> sP (stride 264) -> 16B coalesced stores ----
  #pragma unroll
  for (int mi = 0; mi < 2; mi++)
    #pragma unroll
    for (int ni = 0; ni < 4; ni++) {
      const int col = wn4 * 64 + ni * 16 + lm;
      #pragma unroll
      for (int r = 0; r < 4; r++) {
        const int rl = wm2 * 32 + mi * 16 + qd * 4 + r;   // 0..63
        sP[rl * 264 + col] = f2b(Y[mi][ni][r]);
      }
    }
  __syncthreads();
  #pragma unroll
  for (int it = 0; it < 4; it++) {
    const int idx = it * 512 + t;          // 0..2047 = 64 rows x 32 x 16B
    const int row = idx >> 5, u = idx & 31;
    short8 v = *(const short8*)&sP[row * 264 + u * 8];
    *(short8*)(Qm + (long long)row * 2048 + u * 8) = v;
  }
}

// ---------------------------------------------------------------------------
__global__ void ln_kernel(const float* __restrict__ X,
                          const float* __restrict__ gam,
                          const float* __restrict__ bet,
                          unsigned short* __restrict__ out)
{
  const int g = blockIdx.x * 4 + (threadIdx.x >> 6);
  const int lane = threadIdx.x & 63;
  floatx4 v = *(const floatx4*)(X + (long long)g * 256 + lane * 4);
  float s = v[0] + v[1] + v[2] + v[3];
  float sq = v[0]*v[0] + v[1]*v[1] + v[2]*v[2] + v[3]*v[3];
  #pragma unroll
  for (int off = 32; off > 0; off >>= 1) {
    s  += __shfl_xor(s, off);
    sq += __shfl_xor(sq, off);
  }
  const float mean = s * (1.0f / 256.0f);
  const float var = sq * (1.0f / 256.0f) - mean * mean;
  const float rs = 1.0f / sqrtf(var + 1e-5f);
  ushort4v o;
  #pragma unroll
  for (int jj = 0; jj < 4; jj++) {
    const int c = lane * 4 + jj;
    o[jj] = f2b((v[jj] - mean) * rs * gam[c] + bet[c]);
  }
  *(ushort4v*)(out + (long long)g * 256 + lane * 4) = o;
}

// ---------------------------------------------------------------------------
static inline void launch_gemm(hipStream_t st, int M, int N, int batch,
    const void* A, int lda, long long sAo, long long sAi,
    const void* B, int ldb, long long sBo, long long sBi,
    void* C, int ldc, long long sCo, long long sCi,
    int K, int zshift, int mode, int flag,
    const float* aux1, const float* mask, float* gcn, void* aux2)
{
  dim3 grid(M / 128, N / 128, batch), blk(512);
  gemm_kernel<<<grid, blk, 0, st>>>(
      (const unsigned short*)A, lda, sAo, sAi,
      (const unsigned short*)B, ldb, sBo, sBi,
      C, ldc, sCo, sCi, K, zshift, mode, flag, aux1, mask, gcn, aux2);
}

extern "C" void kernel_launch(void* const* d_in, const int* in_sizes, int n_in,
                              void* d_out, int out_size, void* d_ws, size_t ws_size,
                              hipStream_t stream)
{
  (void)in_sizes; (void)n_in; (void)out_size;
  const float* x    = (const float*)d_in[0];
  const float* adj  = (const float*)d_in[1];
  const float* mask = (const float*)d_in[2];
  const float* dist = (const float*)d_in[3];
  const float* W1   = (const float*)d_in[4];
  const float* b1   = (const float*)d_in[5];
  const float* W2   = (const float*)d_in[6];
  const float* b2   = (const float*)d_in[7];
  const float* W3   = (const float*)d_in[8];
  const float* b3   = (const float*)d_in[9];
  const float* ln1g = (const float*)d_in[10];
  const float* ln1b = (const float*)d_in[11];
  const float* Wq   = (const float*)d_in[12];
  const float* Wk   = (const float*)d_in[13];
  const float* Wv   = (const float*)d_in[14];
  const float* Wo   = (const float*)d_in[15];
  const float* bo   = (const float*)d_in[16];
  const float* ln2g = (const float*)d_in[17];
  const float* ln2b = (const float*)d_in[18];
  const float* Wf1  = (const float*)d_in[19];
  const float* bf1  = (const float*)d_in[20];
  const float* Wf2  = (const float*)d_in[21];
  const float* bf2  = (const float*)d_in[22];

  char* w = (char*)d_ws;
  auto alloc = [&](size_t sz) { void* p = (void*)w; w += sz; return p; };
  // persistent (~61 MB)
  unsigned short* W1T   = (unsigned short*)alloc(65536);      // (256,128)
  unsigned short* W2T   = (unsigned short*)alloc(131072);     // (256,256)
  unsigned short* W3T   = (unsigned short*)alloc(131072);
  unsigned short* ABH   = (unsigned short*)alloc(1048576);    // (2048,256) = Wk_h Wq_h^T /16
  unsigned short* WVT   = (unsigned short*)alloc(1048576);    // (2048,256)
  unsigned short* WOT   = (unsigned short*)alloc(1048576);    // (256,2048)
  unsigned short* WF1T  = (unsigned short*)alloc(524288);     // (1024,256)
  unsigned short* WF2T  = (unsigned short*)alloc(524288);     // (256,1024)
  unsigned short* WQb   = (unsigned short*)alloc(1048576);    // (256,2048) plain
  unsigned short* WKb   = (unsigned short*)alloc(1048576);    // (256,2048) plain
  unsigned short* XBF   = (unsigned short*)alloc(4194304);    // (16384,128)
  unsigned short* DSTB  = (unsigned short*)alloc(8388608);    // (64,256,256) bf16 dist
  float*          GCN   = (float*)         alloc(16777216);   // (16384,256)
  float*          U     = (float*)         alloc(16777216);   // ATT f32
  unsigned short* HBF   = (unsigned short*)alloc(8388608);    // (16384,256)
  float*          DIS   = (float*)         alloc(65536);
  // scratch union (peak = attention: 134.2 MB)
  char* scratch = (char*)alloc(134217728);
  if ((size_t)(w - (char*)d_ws) > ws_size) return;
  // gcn phase views
  unsigned short* AN  = (unsigned short*)scratch;              // 8.4 MB
  unsigned short* TT  = (unsigned short*)(scratch + 8388608);  // 8.4 MB
  unsigned short* GBF = (unsigned short*)(scratch + 16777216); // 8.4 MB
  // attention phase views
  unsigned short* QPB = (unsigned short*)scratch;                 // (16384,2048) 67 MB  Q'->Y
  unsigned short* VT  = (unsigned short*)(scratch + 67108864);    // (512,256,256) 67 MB
  // ffn phase view
  unsigned short* FFB = (unsigned short*)scratch;                 // 33.6 MB

  // ---- single packing launch: 7 transposes + 4 plain cvts ----
  PackArgs pa;
  const float* srcs[11] = {W1, W2, W3, Wv, Wo, Wf1, Wf2, x, Wq, Wk, dist};
  unsigned short* dsts[11] = {W1T, W2T, W3T, WVT, WOT, WF1T, WF2T, XBF, WQb, WKb, DSTB};
  const int Rs[11] = {128, 256, 256, 256, 2048, 256, 1024,
                      BNROWS * INF_, EE * HH * EE, EE * HH * EE, BB * 65536};
  const int Cs[11] = {256, 256, 256, 2048, 256, 1024, 256, 0, 0, 0, 0};
  const int sts[12] = {0, 32, 96, 160, 672, 1184, 1440, 1696, 3744, 4256, 4768, 8864};
  for (int j = 0; j < 11; j++) {
    pa.src[j] = srcs[j]; pa.dst[j] = dsts[j]; pa.R[j] = Rs[j]; pa.C[j] = Cs[j];
  }
  for (int j = 0; j < 12; j++) pa.start[j] = sts[j];
  pack_kernel<<<8864, 256, 0, stream>>>(pa);

  // ---- adjacency normalization ----
  deg_kernel<<<4096, 256, 0, stream>>>(adj, DIS);
  an_kernel<<<4096, 256, 0, stream>>>(adj, DIS, AN);

  // ---- ABH_h = Wk_h Wq_h^T / 16  (8 heads, tiny batched GEMM) ----
  launch_gemm(stream, 256, 256, 8, WKb, 2048, 256, 0, WQb, 2048, 256, 0,
              ABH, 256, 65536, 0, 256, 0, 13, 0, nullptr, nullptr, nullptr, nullptr);

  // ---- GCN stack ----
  launch_gemm(stream, BNROWS, EE, 1, XBF, 128, 0,0, W1T, 128, 0,0,
              TT, 256, 0,0, 128, 0, 5, 0, nullptr, nullptr, nullptr, nullptr);
  launch_gemm(stream, 256, 256, BB, TT, 256, 65536,0, AN, 256, 65536,0,
              GBF, 256, 0,0, 256, 0, 9, 0, b1, mask, GCN, nullptr);
  launch_gemm(stream, BNROWS, EE, 1, GBF, 256, 0,0, W2T, 256, 0,0,
              TT, 256, 0,0, 256, 0, 5, 0, nullptr, nullptr, nullptr, nullptr);
  launch_gemm(stream, 256, 256, BB, TT, 256, 65536,0, AN, 256, 65536,0,
              GBF, 256, 0,0, 256, 0, 9, 1, b2, mask, GCN, nullptr);
  launch_gemm(stream, BNROWS, EE, 1, GBF, 256, 0,0, W3T, 256, 0,0,
              TT, 256, 0,0, 256, 0, 5, 0, nullptr, nullptr, nullptr, nullptr);
  launch_gemm(stream, 256, 256, BB, TT, 256, 65536,0, AN, 256, 65536,0,
              GBF, 256, 0,0, 256, 0, 9, 1, b3, mask, GCN, nullptr);

  // ---- LN1 ----
  ln_kernel<<<4096, 256, 0, stream>>>(GCN, ln1g, ln1b, HBF);

  // ---- attention: combined Q'(=H·ABH^T)/V GEMM -> fused attn -> Y@Wo ----
  launch_gemm(stream, BNROWS, 4096, 1, HBF, 256, 0,0, ABH, 256, 0,0,
              QPB, 2048, 0,0, 256, 0, 15, 0, nullptr, nullptr, nullptr, VT);
  attn_kernel<<<2048, 512, 0, stream>>>(QPB, HBF, VT, DSTB, mask);
  launch_gemm(stream, BNROWS, EE, 1, QPB, 2048, 0,0, WOT, 2048, 0,0,
              U, 256, 0,0, 2048, 0, 12, 0, bo, mask, GCN, nullptr);

  // ---- LN2 + FFN (final residual fused into FFN2 epilogue) ----
  ln_kernel<<<4096, 256, 0, stream>>>(U, ln2g, ln2b, HBF);
  launch_gemm(stream, BNROWS, FFN, 1, HBF, 256, 0,0, WF1T, 256, 0,0,
              FFB, 1024, 0,0, 256, 0, 3, 0, bf1, nullptr, nullptr, nullptr);
  launch_gemm(stream, BNROWS, EE, 1, FFB, 1024, 0,0, WF2T, 1024, 0,0,
              d_out, 256, 0,0, 1024, 0, 8, 0, bf2, mask, GCN, U);
}

// Round 4
// 464.895 us; speedup vs baseline: 1.0685x; 1.0053x over previous
//
#include <hip/hip_runtime.h>
#include <hip/hip_bf16.h>
#include <cmath>

// Problem constants: B=64, N=256, IN=128, E=256, H=8, F=1024
#define BB 64
#define NNODES 256
#define INF_ 128
#define EE 256
#define HH 8
#define FFN 1024
#define BNROWS 16384   // B*N

typedef __attribute__((ext_vector_type(8))) short short8;
typedef __attribute__((ext_vector_type(4))) float floatx4;
typedef __attribute__((ext_vector_type(4))) unsigned short ushort4v;

__device__ __forceinline__ float b2f(unsigned short u) {
  union { unsigned u32; float f; } w; w.u32 = ((unsigned)u) << 16; return w.f;
}
__device__ __forceinline__ unsigned short f2b(float f) {
  union { float f; unsigned u32; } w; w.f = f;
  unsigned r = w.u32 + 0x7FFFu + ((w.u32 >> 16) & 1u);   // RNE
  return (unsigned short)(r >> 16);
}
// tanh-gelu (max abs dev from exact erf-gelu ~3e-4, far below bf16 rounding)
__device__ __forceinline__ float gelu_f(float x) {
  const float z = 0.7978845608028654f * (x + 0.044715f * x * x * x);
  const float e = __expf(2.0f * z);
  const float th = (e - 1.0f) / (e + 1.0f);
  return 0.5f * x * (1.0f + th);
}

typedef const __attribute__((address_space(1))) void GV;
typedef __attribute__((address_space(3))) void LV;

// async global->LDS: per-lane 16B source, wave-uniform LDS base (+lane*16)
__device__ __forceinline__ void gl_lds16(const unsigned short* g,
                                         unsigned short* l, int lane) {
#if __has_builtin(__builtin_amdgcn_global_load_lds)
  __builtin_amdgcn_global_load_lds((GV*)g, (LV*)l, 16, 0, 0);
#else
  *(short8*)(l + lane * 8) = *(const short8*)g;
#endif
}

#define VMW2() asm volatile("s_waitcnt vmcnt(2)" ::: "memory")
#define VMW0() asm volatile("s_waitcnt vmcnt(0)" ::: "memory")
#define LGW0() asm volatile("s_waitcnt lgkmcnt(0)" ::: "memory")
#define MBAR() do { asm volatile("" ::: "memory"); \
                    __builtin_amdgcn_s_barrier(); \
                    asm volatile("" ::: "memory"); } while (0)

// ---------------------------------------------------------------------------
// One kernel for ALL packing: transpose-cvt jobs + plain cvt jobs (C==0).
// ---------------------------------------------------------------------------
struct PackArgs {
  const float* src[12];
  unsigned short* dst[12];
  int R[12], C[12];
  int start[13];
};

__launch_bounds__(256)
__global__ void pack_kernel(PackArgs a)
{
  __shared__ float tile[32][33];
  const int bid = blockIdx.x;
  int j = 0;
  while (bid >= a.start[j + 1]) j++;
  const int lb = bid - a.start[j];
  const float* src = a.src[j];
  unsigned short* dst = a.dst[j];
  const int R = a.R[j], C = a.C[j];

  if (C == 0) {      // plain cvt, R = element count
    const int i = (lb * 256 + threadIdx.x) * 4;
    if (i >= R) return;
    floatx4 v = *(const floatx4*)(src + i);
    ushort4v o;
    #pragma unroll
    for (int k = 0; k < 4; k++) o[k] = f2b(v[k]);
    *(ushort4v*)(dst + i) = o;
    return;
  }
  const int tpr = C >> 5;
  const int c0 = (lb % tpr) * 32, r0 = (lb / tpr) * 32;
  const int tx = threadIdx.x & 31, ty = threadIdx.x >> 5;
  #pragma unroll
  for (int i = ty; i < 32; i += 8)
    tile[i][tx] = src[(long long)(r0 + i) * C + c0 + tx];
  __syncthreads();
  #pragma unroll
  for (int i = ty; i < 32; i += 8)
    dst[(long long)(c0 + i) * R + r0 + tx] = f2b(tile[tx][i]);
}

// ---------------------------------------------------------------------------
// dis = rsqrt(clip(rowsum(A),1,inf)); A = adj (f32) with diag forced to 1
// ---------------------------------------------------------------------------
__global__ void deg_kernel(const float* __restrict__ adj,
                           float* __restrict__ dis)
{
  const int g = blockIdx.x * 4 + (threadIdx.x >> 6);
  const int lane = threadIdx.x & 63;
  const int i = g & 255;
  floatx4 v = *(const floatx4*)(adj + (long long)g * 256 + lane * 4);
  float s = 0.f;
  #pragma unroll
  for (int jj = 0; jj < 4; jj++) {
    const int j = lane * 4 + jj;
    s += (j == i) ? 1.0f : v[jj];
  }
  #pragma unroll
  for (int off = 32; off > 0; off >>= 1) s += __shfl_xor(s, off);
  if (lane == 0) dis[g] = 1.0f / sqrtf(fmaxf(s, 1.0f));
}

// An[b,i,j] = bf16(dis_i * A_ij * dis_j)
__global__ void an_kernel(const float* __restrict__ adj,
                          const float* __restrict__ dis,
                          unsigned short* __restrict__ An)
{
  const long long base = ((long long)blockIdx.x * 256 + threadIdx.x) * 4;
  const int rowg = (int)(base >> 8);
  const int i = rowg & 255;
  const int brow = rowg & ~255;
  const int j0 = (int)(base & 255);
  const float di = dis[rowg];
  floatx4 v = *(const floatx4*)(adj + base);
  ushort4v o;
  #pragma unroll
  for (int jj = 0; jj < 4; jj++) {
    const int j = j0 + jj;
    const float a = (j == i) ? 1.0f : v[jj];
    o[jj] = f2b(di * dis[brow + j] * a);
  }
  *(ushort4v*)(An + base) = o;
}

// ---------------------------------------------------------------------------
// Batched bf16 MFMA GEMM, tile 128x128, BK=128 chunks, 512 threads (8 waves,
// 2x4), each wave 64x32 (acc[4][2]). A (M,K) rm; B (N,K) rm (always NT).
// LDS rows x 16 slots of 16B; slot s holds k-octet q = s ^ (r&7) (XOR swizzle).
// modes:
//  0: f32 store | 1: bf16 store | 2: f32 accumulate | 3: bf16 gelu(val+aux1[col])
//  5: TT store: b=row>>8,n=row&255 -> bf16 C[b*65536+col*256+n]
//  8: final:  f32 C[row*256+col] = gcn[i]+attf[i]+(val+aux1[col])*mask[row]
//  9: GCN epi (C'=U^T): token=zb*256+col, feat=row; g=relu((val+aux1[feat])*mask[token]);
//     bf16 C[token*256+feat]=g; gcn[...] (flag? += : =) g
// 12: f32 C[row*256+col] = gcn[idx] + (val + aux1[col]) * mask[row]
// 13: bf16 store of val * 0.0625  (ABH with attention scale folded)
// 16: V^T scatter only: z2=(row>>8)*8+(col>>8); bf16
//     aux2[z2*65536+(col&255)*256+(row&255)]
// ---------------------------------------------------------------------------
__launch_bounds__(512, 4)
__global__ void gemm_kernel(const unsigned short* __restrict__ A, int lda,
                            long long sAo, long long sAi,
                            const unsigned short* __restrict__ Bm, int ldb,
                            long long sBo, long long sBi,
                            void* __restrict__ Cv, int ldc,
                            long long sCo, long long sCi,
                            int K, int zshift, int mode, int flag,
                            const float* __restrict__ aux1,
                            const float* __restrict__ mask,
                            float* __restrict__ gcn,
                            void* __restrict__ aux2)
{
  __shared__ __align__(16) unsigned short sA[16384];   // 32KB
  __shared__ __align__(16) unsigned short sB[16384];   // 32KB

  const int t = threadIdx.x;
  const int z = blockIdx.z;
  const int zi = z & ((1 << zshift) - 1);
  const int zb = z >> zshift;
  const int m0 = blockIdx.x * 128;
  const int n0 = blockIdx.y * 128;
  A  += zb * sAo + zi * sAi;
  Bm += zb * sBo + zi * sBi;
  const long long cbase = zb * sCo + zi * sCi;

  const int lane = t & 63;
  const int w = t >> 6;              // wave 0..7
  const int wm = w >> 2, wn = w & 3; // 2 x 4
  const int lm = lane & 15, qd = lane >> 4;

  floatx4 acc[4][2] = {};

  const int sub = lane >> 4;        // 0..3
  const int qs  = lane & 15;        // slot within row
  const unsigned short* pA[4];
  const unsigned short* pB[4];
  #pragma unroll
  for (int i = 0; i < 4; i++) {
    const int d = w * 4 + i;        // DMA index 0..31
    const int r = d * 4 + sub;      // tile row 0..127
    const int co = (qs ^ (r & 7)) * 8;   // swizzled col octet (elements)
    pA[i] = A + (long long)(m0 + r) * lda + co;
    pB[i] = Bm + (long long)(n0 + r) * ldb + co;
  }

  for (int kk = 0; kk < K; kk += 128) {
    #pragma unroll
    for (int i = 0; i < 4; i++) {
      gl_lds16(pA[i] + kk, &sA[(w * 4 + i) * 512], lane);
      gl_lds16(pB[i] + kk, &sB[(w * 4 + i) * 512], lane);
    }
    __syncthreads();

    #pragma unroll
    for (int ks = 0; ks < 4; ks++) {
      short8 af[4], bg[2];
      const int q = ks * 4 + qd;          // k-octet 0..15
      #pragma unroll
      for (int mi = 0; mi < 4; mi++) {
        const int r = wm * 64 + mi * 16 + lm;
        af[mi] = *(const short8*)&sA[r * 128 + ((q ^ (r & 7)) * 8)];
      }
      #pragma unroll
      for (int ni = 0; ni < 2; ni++) {
        const int r = wn * 32 + ni * 16 + lm;
        bg[ni] = *(const short8*)&sB[r * 128 + ((q ^ (r & 7)) * 8)];
      }
      #pragma unroll
      for (int mi = 0; mi < 4; mi++)
        #pragma unroll
        for (int ni = 0; ni < 2; ni++)
          acc[mi][ni] = __builtin_amdgcn_mfma_f32_16x16x32_bf16(
              af[mi], bg[ni], acc[mi][ni], 0, 0, 0);
    }
    __syncthreads();
  }

  // ---- epilogue ----
  #pragma unroll
  for (int mi = 0; mi < 4; mi++) {
    const int row0 = m0 + wm * 64 + mi * 16 + qd * 4;
    #pragma unroll
    for (int ni = 0; ni < 2; ni++) {
      const int col = n0 + wn * 32 + ni * 16 + lm;
      floatx4 a = acc[mi][ni];
      if (mode == 0) {
        float* Cf = (float*)Cv;
        #pragma unroll
        for (int r = 0; r < 4; r++)
          Cf[cbase + (long long)(row0 + r) * ldc + col] = a[r];
      } else if (mode == 1) {
        unsigned short* Cb = (unsigned short*)Cv;
        #pragma unroll
        for (int r = 0; r < 4; r++)
          Cb[cbase + (long long)(row0 + r) * ldc + col] = f2b(a[r]);
      } else if (mode == 2) {
        float* Cf = (float*)Cv;
        #pragma unroll
        for (int r = 0; r < 4; r++)
          Cf[cbase + (long long)(row0 + r) * ldc + col] += a[r];
      } else if (mode == 3) {
        unsigned short* Cb = (unsigned short*)Cv;
        const float bv = aux1[col];
        #pragma unroll
        for (int r = 0; r < 4; r++)
          Cb[cbase + (long long)(row0 + r) * ldc + col] = f2b(gelu_f(a[r] + bv));
      } else if (mode == 5) {
        const int b = row0 >> 8, n = row0 & 255;
        ushort4v o;
        #pragma unroll
        for (int r = 0; r < 4; r++) o[r] = f2b(a[r]);
        *(ushort4v*)((unsigned short*)Cv + (long long)b * 65536 + col * 256 + n) = o;
      } else if (mode == 8) {
        float* Cf = (float*)Cv;
        const float* attf = (const float*)aux2;
        const float bv = aux1[col];
        #pragma unroll
        for (int r = 0; r < 4; r++) {
          const long long idx = (long long)(row0 + r) * 256 + col;
          Cf[idx] = gcn[idx] + attf[idx] + (a[r] + bv) * mask[row0 + r];
        }
      } else if (mode == 9) {
        const int token = zb * 256 + col;
        const float m = mask[token];
        ushort4v o; floatx4 g;
        #pragma unroll
        for (int r = 0; r < 4; r++) {
          const float v = fmaxf((a[r] + aux1[row0 + r]) * m, 0.f);
          o[r] = f2b(v); g[r] = v;
        }
        *(ushort4v*)((unsigned short*)Cv + (long long)token * 256 + row0) = o;
        float* gp = gcn + (long long)token * 256 + row0;
        if (flag) { floatx4 old = *(const floatx4*)gp; g += old; }
        *(floatx4*)gp = g;
      } else if (mode == 12) { // U = GCN + (val + bo)*mask
        float* Cf = (float*)Cv;
        const float bv = aux1[col];
        #pragma unroll
        for (int r = 0; r < 4; r++) {
          const long long idx = (long long)(row0 + r) * 256 + col;
          Cf[idx] = gcn[idx] + (a[r] + bv) * mask[row0 + r];
        }
      } else if (mode == 13) { // scaled bf16 (ABH /16)
        unsigned short* Cb = (unsigned short*)Cv;
        #pragma unroll
        for (int r = 0; r < 4; r++)
          Cb[cbase + (long long)(row0 + r) * ldc + col] = f2b(a[r] * 0.0625f);
      } else { // 16: V^T scatter only (col = h*256 + e)
        const int z2 = (row0 >> 8) * 8 + (col >> 8);
        const int e = col & 255, n = row0 & 255;
        ushort4v o;
        #pragma unroll
        for (int r = 0; r < 4; r++) o[r] = f2b(a[r]);
        *(ushort4v*)((unsigned short*)aux2 + (long long)z2 * 65536 + e * 256 + n) = o;
      }
    }
  }
}

// ---------------------------------------------------------------------------
// Fused attention v10 (= v9 with the staging ledger fixed):
//  * Q' = H_q * ABH_h^T computed IN-KERNEL; ABH/H/V^T are 24 uniform 16 KB
//    chunks (256 rows x 64 B), double-buffered in 2x16 KB.
//  * FIX vs v9: staging is CONTINUOUS across phase boundaries — every
//    iteration does {compute(c); MBAR; STAGE(c+2); VMW2; MBAR}, so the
//    2-deep invariant (4 outstanding at each VMW2 -> chunk c+1 retired)
//    holds everywhere.  v9 never staged chunks 8/16 and had tail
//    iterations where vmcnt(2) was a no-op (outstanding==2) -> races +
//    stale data (absmax 2.17).  Transitions now need no stage/wait; only
//    phase-3's last prefetchless iteration (c=22) drains with vmcnt(0).
//  * sR0 (33 KB) time-shared: H_q -> Q' -> P planes -> Y epilogue, each
//    transition guarded by the post-compute barrier of the consuming phase.
//  * LDS 68.6 KB, 2 blocks/CU preserved (16 waves; sibling-block TLP on
//    top of the in-block pipeline).
// ---------------------------------------------------------------------------
__launch_bounds__(512, 4)
__global__ void attn_kernel(unsigned short* __restrict__ QP,   // (16384,2048) Y out
                            const unsigned short* __restrict__ HBF, // (16384,256)
                            const unsigned short* __restrict__ ABH, // (2048,256)
                            const unsigned short* __restrict__ VT,  // (512,256,256)
                            const unsigned short* __restrict__ DSTB,// (64,256,256) bf16
                            const float* __restrict__ mask)
{
  __shared__ __align__(16) unsigned short sR0[16896];  // 33KB: Hq -> Q' -> P -> Yepi
  __shared__ __align__(16) unsigned short sS[16384];   // 32KB: 2 x 16KB stream bufs
  __shared__ float redm[4][64];
  __shared__ float reds[4][64];

  // XCD swizzle: the 8 h-blocks of one (b,mt) share an XCD (same bi&7 under
  // round-robin) so H_b and the dist tile are L2-deduped.
  const int bi = blockIdx.x;              // 0..2047
  const int x = bi & 7;
  const int h = (bi >> 3) & 7;
  const int p = (bi >> 6) * 8 + x;        // 0..255 : (b,mt) group id
  const int b = p >> 2, mt = p & 3;
  const int m0 = mt * 64;
  const int z = b * 8 + h;

  const int t = threadIdx.x, lane = t & 63, w = t >> 6;
  const int lm = lane & 15, qd = lane >> 4;
  const int wm2 = w >> 2, wn4 = w & 3;    // 2 row-groups x 4 key/e-groups

  unsigned short* Ym = QP + ((long long)(b * 256 + m0)) * 2048 + h * 256;
  const unsigned short* Hb = HBF + (long long)b * 65536;
  const unsigned short* Hq = Hb + (long long)m0 * 256;
  const unsigned short* Ah = ABH + (long long)h * 65536;
  const unsigned short* Vb = VT + (long long)z * 65536;
  const unsigned short* db = DSTB + (long long)b * 65536 + (long long)m0 * 256;
  const float* maskb = mask + b * 256;

  // ---- dist preload (oldest vmem ops; compiler auto-waits before first
  //      use; becomes the S-phase MFMA C-in, folding "+dist" into MFMA) ----
  floatx4 S[2][4];
  #pragma unroll
  for (int mi = 0; mi < 2; mi++)
    #pragma unroll
    for (int ni = 0; ni < 4; ni++) {
      const int col = wn4 * 64 + ni * 16 + lm;
      #pragma unroll
      for (int r = 0; r < 4; r++) {
        const int row = wm2 * 32 + mi * 16 + qd * 4 + r;
        S[mi][ni][r] = b2f(db[row * 256 + col]);
      }
    }

  // ---- per-thread staging geometry (all 24 chunks: 256 rows x 64 B) ----
  int eoff0, eoff1;
  {
    const int rA = lane >> 2, sl = lane & 3;
    const int r0 = (w * 2 + 0) * 16 + rA;
    const int r1 = (w * 2 + 1) * 16 + rA;
    eoff0 = r0 * 256 + ((sl ^ ((r0 >> 1) & 3)) * 8);
    eoff1 = r1 * 256 + ((sl ^ ((r1 >> 1) & 3)) * 8);
  }
  const int ld0 = (w * 2 + 0) * 512;
  const int ld1 = (w * 2 + 1) * 512;

  auto STAGE = [&](int c) {
    const unsigned short* bp =
        (c < 8 ? Ah : (c < 16 ? Hb : Vb)) + (c & 7) * 32;
    const int bb = (c & 1) * 8192;
    gl_lds16(bp + eoff0, &sS[bb + ld0], lane);
    gl_lds16(bp + eoff1, &sS[bb + ld1], lane);
  };

  // ---- prologue: H_q tile (32 KB -> sR0) + chunks 0,1 ----
  {
    const int rin2 = lane >> 5, qs32 = lane & 31;
    #pragma unroll
    for (int i = 0; i < 4; i++) {
      const int d = w * 4 + i;
      const int r = d * 2 + rin2;          // H_q row 0..63
      gl_lds16(Hq + (long long)r * 256 + ((qs32 ^ (r & 7)) * 8),
               &sR0[d * 512], lane);
    }
  }
  STAGE(0); STAGE(1);
  VMW2();                                  // dist + H_q + chunk0 retired
  MBAR();

  // ---- phase 1: Q' = H_q * ABH_h^T  (chunks 0..7) ----
  floatx4 accq[2][4] = {};
  #pragma unroll
  for (int c = 0; c < 8; c++) {
    __builtin_amdgcn_s_setprio(1);
    short8 af[2], bg[4];
    #pragma unroll
    for (int mi = 0; mi < 2; mi++) {
      const int r = wm2 * 32 + mi * 16 + lm;
      const int q = c * 4 + qd;
      af[mi] = *(const short8*)&sR0[r * 256 + ((q ^ (r & 7)) * 8)];
    }
    const int bb = (c & 1) * 8192;
    #pragma unroll
    for (int ni = 0; ni < 4; ni++) {
      const int rr = wn4 * 64 + ni * 16 + lm;
      bg[ni] = *(const short8*)&sS[bb + rr * 32 + ((qd ^ ((rr >> 1) & 3)) * 8)];
    }
    #pragma unroll
    for (int mi = 0; mi < 2; mi++)
      #pragma unroll
      for (int ni = 0; ni < 4; ni++)
        accq[mi][ni] = __builtin_amdgcn_mfma_f32_16x16x32_bf16(
            af[mi], bg[ni], accq[mi][ni], 0, 0, 0);
    __builtin_amdgcn_s_setprio(0);
    MBAR();                                // all waves done with buf c&1
    STAGE(c + 2);                          // chunks 2..9 (continuous)
    VMW2();                                // chunk c+1 retired
    MBAR();
  }

  // ---- transition: materialize Q' bf16 into sR0 (chunks 8,9 in flight) ----
  #pragma unroll
  for (int mi = 0; mi < 2; mi++)
    #pragma unroll
    for (int rr = 0; rr < 4; rr++) {
      const int row = wm2 * 32 + mi * 16 + qd * 4 + rr;
      #pragma unroll
      for (int ni = 0; ni < 4; ni++) {
        const int col = wn4 * 64 + ni * 16 + lm;
        const int o = col >> 3;
        sR0[row * 256 + ((o ^ (row & 7)) * 8) + (col & 7)] = f2b(accq[mi][ni][rr]);
      }
    }
  LGW0();
  MBAR();                                  // Q' visible to all waves

  // ---- phase 2: S = Q' * H^T + dist  (chunks 8..15) ----
  #pragma unroll
  for (int c = 8; c < 16; c++) {
    __builtin_amdgcn_s_setprio(1);
    short8 af[2], bg[4];
    #pragma unroll
    for (int mi = 0; mi < 2; mi++) {
      const int r = wm2 * 32 + mi * 16 + lm;
      const int q = (c - 8) * 4 + qd;
      af[mi] = *(const short8*)&sR0[r * 256 + ((q ^ (r & 7)) * 8)];
    }
    const int bb = (c & 1) * 8192;
    #pragma unroll
    for (int ni = 0; ni < 4; ni++) {
      const int rr = wn4 * 64 + ni * 16 + lm;
      bg[ni] = *(const short8*)&sS[bb + rr * 32 + ((qd ^ ((rr >> 1) & 3)) * 8)];
    }
    #pragma unroll
    for (int mi = 0; mi < 2; mi++)
      #pragma unroll
      for (int ni = 0; ni < 4; ni++)
        S[mi][ni] = __builtin_amdgcn_mfma_f32_16x16x32_bf16(
            af[mi], bg[ni], S[mi][ni], 0, 0, 0);
    __builtin_amdgcn_s_setprio(0);
    MBAR();
    STAGE(c + 2);                          // chunks 10..17 (continuous)
    VMW2();
    MBAR();
  }

  // ---- transition: softmax; P planes into sR0 (chunks 16,17 staged) ----
  float mkv[4];
  #pragma unroll
  for (int ni = 0; ni < 4; ni++) mkv[ni] = maskb[wn4 * 64 + ni * 16 + lm];

  float lred[2][4];
  #pragma unroll
  for (int mi = 0; mi < 2; mi++) {
    #pragma unroll
    for (int r = 0; r < 4; r++) {
      const int row = wm2 * 32 + mi * 16 + qd * 4 + r;
      const float mq = maskb[m0 + row];
      float mx = -3e38f;
      #pragma unroll
      for (int ni = 0; ni < 4; ni++) {
        const float v = (mq != 0.f && mkv[ni] != 0.f) ? S[mi][ni][r] : -1e9f;
        S[mi][ni][r] = v;
        mx = fmaxf(mx, v);
      }
      lred[mi][r] = mx;
    }
  }
  #pragma unroll
  for (int off = 1; off < 16; off <<= 1)
    #pragma unroll
    for (int mi = 0; mi < 2; mi++)
      #pragma unroll
      for (int r = 0; r < 4; r++)
        lred[mi][r] = fmaxf(lred[mi][r], __shfl_xor(lred[mi][r], off));
  if (lm == 0)
    #pragma unroll
    for (int mi = 0; mi < 2; mi++)
      #pragma unroll
      for (int r = 0; r < 4; r++)
        redm[wn4][wm2 * 32 + mi * 16 + qd * 4 + r] = lred[mi][r];
  LGW0();
  MBAR();

  #pragma unroll
  for (int mi = 0; mi < 2; mi++) {
    #pragma unroll
    for (int r = 0; r < 4; r++) {
      const int row = wm2 * 32 + mi * 16 + qd * 4 + r;
      const float gmax = fmaxf(fmaxf(redm[0][row], redm[1][row]),
                               fmaxf(redm[2][row], redm[3][row]));
      float ss = 0.f;
      #pragma unroll
      for (int ni = 0; ni < 4; ni++) {
        const float e = __expf(S[mi][ni][r] - gmax);   // invalid -> exactly 0
        S[mi][ni][r] = e;
        ss += e;
      }
      lred[mi][r] = ss;
    }
  }
  #pragma unroll
  for (int off = 1; off < 16; off <<= 1)
    #pragma unroll
    for (int mi = 0; mi < 2; mi++)
      #pragma unroll
      for (int r = 0; r < 4; r++)
        lred[mi][r] += __shfl_xor(lred[mi][r], off);
  if (lm == 0)
    #pragma unroll
    for (int mi = 0; mi < 2; mi++)
      #pragma unroll
      for (int r = 0; r < 4; r++)
        reds[wn4][wm2 * 32 + mi * 16 + qd * 4 + r] = lred[mi][r];
  LGW0();
  MBAR();

  // normalize; P planes [wn4][64 rows][64 keys] (128B rows; overwrites Q')
  #pragma unroll
  for (int mi = 0; mi < 2; mi++)
    #pragma unroll
    for (int r = 0; r < 4; r++) {
      const int row = wm2 * 32 + mi * 16 + qd * 4 + r;
      const float inv = 1.0f / (reds[0][row] + reds[1][row] +
                                reds[2][row] + reds[3][row]);
      #pragma unroll
      for (int ni = 0; ni < 4; ni++) {
        const int kl = ni * 16 + lm;
        const int slot = (kl >> 3) ^ (row & 7);
        sR0[wn4 * 4096 + row * 64 + slot * 8 + (kl & 7)] =
            f2b(S[mi][ni][r] * inv);
      }
    }
  LGW0();
  MBAR();                                  // P visible

  // ---- phase 3: Y = P * V  (chunks 16..23) ----
  floatx4 Y[2][4] = {};
  #pragma unroll
  for (int c = 16; c < 24; c++) {
    __builtin_amdgcn_s_setprio(1);
    const int pp = (c - 16) >> 1;
    const int op = ((c - 16) & 1) * 4 + qd;
    short8 af[2], bg[4];
    #pragma unroll
    for (int mi = 0; mi < 2; mi++) {
      const int r = wm2 * 32 + mi * 16 + lm;
      af[mi] = *(const short8*)&sR0[pp * 4096 + r * 64 + ((op ^ (r & 7)) * 8)];
    }
    const int bb = (c & 1) * 8192;
    #pragma unroll
    for (int ni = 0; ni < 4; ni++) {
      const int rr = wn4 * 64 + ni * 16 + lm;
      bg[ni] = *(const short8*)&sS[bb + rr * 32 + ((qd ^ ((rr >> 1) & 3)) * 8)];
    }
    #pragma unroll
    for (int mi = 0; mi < 2; mi++)
      #pragma unroll
      for (int ni = 0; ni < 4; ni++)
        Y[mi][ni] = __builtin_amdgcn_mfma_f32_16x16x32_bf16(
            af[mi], bg[ni], Y[mi][ni], 0, 0, 0);
    __builtin_amdgcn_s_setprio(0);
    MBAR();
    if (c < 22) {
      STAGE(c + 2);                        // chunks 18..23
      VMW2();
      MBAR();
    } else if (c == 22) {
      VMW0();                              // drain chunk 23 (no prefetch left)
      MBAR();
    }
  }

  // ---- epilogue: Y -> sR0 (stride 264) -> 16B coalesced stores ----
  #pragma unroll
  for (int mi = 0; mi < 2; mi++)
    #pragma unroll
    for (int ni = 0; ni < 4; ni++) {
      const int col = wn4 * 64 + ni * 16 + lm;
      #pragma unroll
      for (int r = 0; r < 4; r++) {
        const int rl = wm2 * 32 + mi * 16 + qd * 4 + r;   // 0..63
        sR0[rl * 264 + col] = f2b(Y[mi][ni][r]);
      }
    }
  LGW0();
  MBAR();
  #pragma unroll
  for (int it = 0; it < 4; it++) {
    const int idx = it * 512 + t;          // 0..2047 = 64 rows x 32 x 16B
    const int row = idx >> 5, u = idx & 31;
    short8 v = *(const short8*)&sR0[row * 264 + u * 8];
    *(short8*)(Ym + (long long)row * 2048 + u * 8) = v;
  }
}

// ---------------------------------------------------------------------------
__global__ void ln_kernel(const float* __restrict__ X,
                          const float* __restrict__ gam,
                          const float* __restrict__ bet,
                          unsigned short* __restrict__ out)
{
  const int g = blockIdx.x * 4 + (threadIdx.x >> 6);
  const int lane = threadIdx.x & 63;
  floatx4 v = *(const floatx4*)(X + (long long)g * 256 + lane * 4);
  float s = v[0] + v[1] + v[2] + v[3];
  float sq = v[0]*v[0] + v[1]*v[1] + v[2]*v[2] + v[3]*v[3];
  #pragma unroll
  for (int off = 32; off > 0; off >>= 1) {
    s  += __shfl_xor(s, off);
    sq += __shfl_xor(sq, off);
  }
  const float mean = s * (1.0f / 256.0f);
  const float var = sq * (1.0f / 256.0f) - mean * mean;
  const float rs = 1.0f / sqrtf(var + 1e-5f);
  ushort4v o;
  #pragma unroll
  for (int jj = 0; jj < 4; jj++) {
    const int c = lane * 4 + jj;
    o[jj] = f2b((v[jj] - mean) * rs * gam[c] + bet[c]);
  }
  *(ushort4v*)(out + (long long)g * 256 + lane * 4) = o;
}

// ---------------------------------------------------------------------------
static inline void launch_gemm(hipStream_t st, int M, int N, int batch,
    const void* A, int lda, long long sAo, long long sAi,
    const void* B, int ldb, long long sBo, long long sBi,
    void* C, int ldc, long long sCo, long long sCi,
    int K, int zshift, int mode, int flag,
    const float* aux1, const float* mask, float* gcn, void* aux2)
{
  dim3 grid(M / 128, N / 128, batch), blk(512);
  gemm_kernel<<<grid, blk, 0, st>>>(
      (const unsigned short*)A, lda, sAo, sAi,
      (const unsigned short*)B, ldb, sBo, sBi,
      C, ldc, sCo, sCi, K, zshift, mode, flag, aux1, mask, gcn, aux2);
}

extern "C" void kernel_launch(void* const* d_in, const int* in_sizes, int n_in,
                              void* d_out, int out_size, void* d_ws, size_t ws_size,
                              hipStream_t stream)
{
  (void)in_sizes; (void)n_in; (void)out_size;
  const float* x    = (const float*)d_in[0];
  const float* adj  = (const float*)d_in[1];
  const float* mask = (const float*)d_in[2];
  const float* dist = (const float*)d_in[3];
  const float* W1   = (const float*)d_in[4];
  const float* b1   = (const float*)d_in[5];
  const float* W2   = (const float*)d_in[6];
  const float* b2   = (const float*)d_in[7];
  const float* W3   = (const float*)d_in[8];
  const float* b3   = (const float*)d_in[9];
  const float* ln1g = (const float*)d_in[10];
  const float* ln1b = (const float*)d_in[11];
  const float* Wq   = (const float*)d_in[12];
  const float* Wk   = (const float*)d_in[13];
  const float* Wv   = (const float*)d_in[14];
  const float* Wo   = (const float*)d_in[15];
  const float* bo   = (const float*)d_in[16];
  const float* ln2g = (const float*)d_in[17];
  const float* ln2b = (const float*)d_in[18];
  const float* Wf1  = (const float*)d_in[19];
  const float* bf1  = (const float*)d_in[20];
  const float* Wf2  = (const float*)d_in[21];
  const float* bf2  = (const float*)d_in[22];

  char* w = (char*)d_ws;
  auto alloc = [&](size_t sz) { void* p = (void*)w; w += sz; return p; };
  // persistent (~61 MB)
  unsigned short* W1T   = (unsigned short*)alloc(65536);      // (256,128)
  unsigned short* W2T   = (unsigned short*)alloc(131072);     // (256,256)
  unsigned short* W3T   = (unsigned short*)alloc(131072);
  unsigned short* ABH   = (unsigned short*)alloc(1048576);    // (2048,256) = Wk_h Wq_h^T /16
  unsigned short* WVT   = (unsigned short*)alloc(1048576);    // (2048,256)
  unsigned short* WOT   = (unsigned short*)alloc(1048576);    // (256,2048)
  unsigned short* WF1T  = (unsigned short*)alloc(524288);     // (1024,256)
  unsigned short* WF2T  = (unsigned short*)alloc(524288);     // (256,1024)
  unsigned short* WQb   = (unsigned short*)alloc(1048576);    // (256,2048) plain
  unsigned short* WKb   = (unsigned short*)alloc(1048576);    // (256,2048) plain
  unsigned short* XBF   = (unsigned short*)alloc(4194304);    // (16384,128)
  unsigned short* DSTB  = (unsigned short*)alloc(8388608);    // (64,256,256) bf16 dist
  float*          GCN   = (float*)         alloc(16777216);   // (16384,256)
  float*          U     = (float*)         alloc(16777216);   // ATT f32
  unsigned short* HBF   = (unsigned short*)alloc(8388608);    // (16384,256)
  float*          DIS   = (float*)         alloc(65536);
  // scratch union (peak = attention: 134.2 MB)
  char* scratch = (char*)alloc(134217728);
  if ((size_t)(w - (char*)d_ws) > ws_size) return;
  // gcn phase views
  unsigned short* AN  = (unsigned short*)scratch;              // 8.4 MB
  unsigned short* TT  = (unsigned short*)(scratch + 8388608);  // 8.4 MB
  unsigned short* GBF = (unsigned short*)(scratch + 16777216); // 8.4 MB
  // attention phase views
  unsigned short* QPB = (unsigned short*)scratch;                 // (16384,2048) 67 MB  Y
  unsigned short* VT  = (unsigned short*)(scratch + 67108864);    // (512,256,256) 67 MB
  // ffn phase view
  unsigned short* FFB = (unsigned short*)scratch;                 // 33.6 MB

  // ---- single packing launch: 7 transposes + 4 plain cvts ----
  PackArgs pa;
  const float* srcs[11] = {W1, W2, W3, Wv, Wo, Wf1, Wf2, x, Wq, Wk, dist};
  unsigned short* dsts[11] = {W1T, W2T, W3T, WVT, WOT, WF1T, WF2T, XBF, WQb, WKb, DSTB};
  const int Rs[11] = {128, 256, 256, 256, 2048, 256, 1024,
                      BNROWS * INF_, EE * HH * EE, EE * HH * EE, BB * 65536};
  const int Cs[11] = {256, 256, 256, 2048, 256, 1024, 256, 0, 0, 0, 0};
  const int sts[12] = {0, 32, 96, 160, 672, 1184, 1440, 1696, 3744, 4256, 4768, 8864};
  for (int j = 0; j < 11; j++) {
    pa.src[j] = srcs[j]; pa.dst[j] = dsts[j]; pa.R[j] = Rs[j]; pa.C[j] = Cs[j];
  }
  for (int j = 0; j < 12; j++) pa.start[j] = sts[j];
  pack_kernel<<<8864, 256, 0, stream>>>(pa);

  // ---- adjacency normalization ----
  deg_kernel<<<4096, 256, 0, stream>>>(adj, DIS);
  an_kernel<<<4096, 256, 0, stream>>>(adj, DIS, AN);

  // ---- ABH_h = Wk_h Wq_h^T / 16  (8 heads, tiny batched GEMM) ----
  launch_gemm(stream, 256, 256, 8, WKb, 2048, 256, 0, WQb, 2048, 256, 0,
              ABH, 256, 65536, 0, 256, 0, 13, 0, nullptr, nullptr, nullptr, nullptr);

  // ---- GCN stack ----
  launch_gemm(stream, BNROWS, EE, 1, XBF, 128, 0,0, W1T, 128, 0,0,
              TT, 256, 0,0, 128, 0, 5, 0, nullptr, nullptr, nullptr, nullptr);
  launch_gemm(stream, 256, 256, BB, TT, 256, 65536,0, AN, 256, 65536,0,
              GBF, 256, 0,0, 256, 0, 9, 0, b1, mask, GCN, nullptr);
  launch_gemm(stream, BNROWS, EE, 1, GBF, 256, 0,0, W2T, 256, 0,0,
              TT, 256, 0,0, 256, 0, 5, 0, nullptr, nullptr, nullptr, nullptr);
  launch_gemm(stream, 256, 256, BB, TT, 256, 65536,0, AN, 256, 65536,0,
              GBF, 256, 0,0, 256, 0, 9, 1, b2, mask, GCN, nullptr);
  launch_gemm(stream, BNROWS, EE, 1, GBF, 256, 0,0, W3T, 256, 0,0,
              TT, 256, 0,0, 256, 0, 5, 0, nullptr, nullptr, nullptr, nullptr);
  launch_gemm(stream, 256, 256, BB, TT, 256, 65536,0, AN, 256, 65536,0,
              GBF, 256, 0,0, 256, 0, 9, 1, b3, mask, GCN, nullptr);

  // ---- LN1 ----
  ln_kernel<<<4096, 256, 0, stream>>>(GCN, ln1g, ln1b, HBF);

  // ---- attention: V^T GEMM -> fused attn (Q' in-kernel) -> Y@Wo ----
  launch_gemm(stream, BNROWS, 2048, 1, HBF, 256, 0,0, WVT, 256, 0,0,
              QPB, 2048, 0,0, 256, 0, 16, 0, nullptr, nullptr, nullptr, VT);
  attn_kernel<<<2048, 512, 0, stream>>>(QPB, HBF, ABH, VT, DSTB, mask);
  launch_gemm(stream, BNROWS, EE, 1, QPB, 2048, 0,0, WOT, 2048, 0,0,
              U, 256, 0,0, 2048, 0, 12, 0, bo, mask, GCN, nullptr);

  // ---- LN2 + FFN (final residual fused into FFN2 epilogue) ----
  ln_kernel<<<4096, 256, 0, stream>>>(U, ln2g, ln2b, HBF);
  launch_gemm(stream, BNROWS, FFN, 1, HBF, 256, 0,0, WF1T, 256, 0,0,
              FFB, 1024, 0,0, 256, 0, 3, 0, bf1, nullptr, nullptr, nullptr);
  launch_gemm(stream, BNROWS, EE, 1, FFB, 1024, 0,0, WF2T, 1024, 0,0,
              d_out, 256, 0,0, 1024, 0, 8, 0, bf2, mask, GCN, U);
}

// Round 6
// 453.335 us; speedup vs baseline: 1.0958x; 1.0255x over previous
//
#include <hip/hip_runtime.h>
#include <hip/hip_bf16.h>
#include <cmath>

// Problem constants: B=64, N=256, IN=128, E=256, H=8, F=1024
#define BB 64
#define NNODES 256
#define INF_ 128
#define EE 256
#define HH 8
#define FFN 1024
#define BNROWS 16384   // B*N

typedef __attribute__((ext_vector_type(8))) short short8;
typedef __attribute__((ext_vector_type(4))) float floatx4;
typedef __attribute__((ext_vector_type(4))) unsigned short ushort4v;

__device__ __forceinline__ float b2f(unsigned short u) {
  union { unsigned u32; float f; } w; w.u32 = ((unsigned)u) << 16; return w.f;
}
__device__ __forceinline__ unsigned short f2b(float f) {
  union { float f; unsigned u32; } w; w.f = f;
  unsigned r = w.u32 + 0x7FFFu + ((w.u32 >> 16) & 1u);   // RNE
  return (unsigned short)(r >> 16);
}
// tanh-gelu (max abs dev from exact erf-gelu ~3e-4, far below bf16 rounding)
__device__ __forceinline__ float gelu_f(float x) {
  const float z = 0.7978845608028654f * (x + 0.044715f * x * x * x);
  const float e = __expf(2.0f * z);
  const float th = (e - 1.0f) / (e + 1.0f);
  return 0.5f * x * (1.0f + th);
}

typedef const __attribute__((address_space(1))) void GV;
typedef __attribute__((address_space(3))) void LV;

// async global->LDS: per-lane 16B source, wave-uniform LDS base (+lane*16)
__device__ __forceinline__ void gl_lds16(const unsigned short* g,
                                         unsigned short* l, int lane) {
#if __has_builtin(__builtin_amdgcn_global_load_lds)
  __builtin_amdgcn_global_load_lds((GV*)g, (LV*)l, 16, 0, 0);
#else
  *(short8*)(l + lane * 8) = *(const short8*)g;
#endif
}

#define VMW2() asm volatile("s_waitcnt vmcnt(2)" ::: "memory")
#define VMW0() asm volatile("s_waitcnt vmcnt(0)" ::: "memory")
#define LGW0() asm volatile("s_waitcnt lgkmcnt(0)" ::: "memory")
#define MBAR() do { asm volatile("" ::: "memory"); \
                    __builtin_amdgcn_s_barrier(); \
                    asm volatile("" ::: "memory"); } while (0)

// ---------------------------------------------------------------------------
// One kernel for ALL packing: transpose-cvt jobs + plain cvt jobs (C==0).
// ---------------------------------------------------------------------------
struct PackArgs {
  const float* src[12];
  unsigned short* dst[12];
  int R[12], C[12];
  int start[13];
};

__launch_bounds__(256)
__global__ void pack_kernel(PackArgs a)
{
  __shared__ float tile[32][33];
  const int bid = blockIdx.x;
  int j = 0;
  while (bid >= a.start[j + 1]) j++;
  const int lb = bid - a.start[j];
  const float* src = a.src[j];
  unsigned short* dst = a.dst[j];
  const int R = a.R[j], C = a.C[j];

  if (C == 0) {      // plain cvt, R = element count
    const int i = (lb * 256 + threadIdx.x) * 4;
    if (i >= R) return;
    floatx4 v = *(const floatx4*)(src + i);
    ushort4v o;
    #pragma unroll
    for (int k = 0; k < 4; k++) o[k] = f2b(v[k]);
    *(ushort4v*)(dst + i) = o;
    return;
  }
  const int tpr = C >> 5;
  const int c0 = (lb % tpr) * 32, r0 = (lb / tpr) * 32;
  const int tx = threadIdx.x & 31, ty = threadIdx.x >> 5;
  #pragma unroll
  for (int i = ty; i < 32; i += 8)
    tile[i][tx] = src[(long long)(r0 + i) * C + c0 + tx];
  __syncthreads();
  #pragma unroll
  for (int i = ty; i < 32; i += 8)
    dst[(long long)(c0 + i) * R + r0 + tx] = f2b(tile[tx][i]);
}

// ---------------------------------------------------------------------------
// dis = rsqrt(clip(rowsum(A),1,inf)); A = adj (f32) with diag forced to 1
// ---------------------------------------------------------------------------
__global__ void deg_kernel(const float* __restrict__ adj,
                           float* __restrict__ dis)
{
  const int g = blockIdx.x * 4 + (threadIdx.x >> 6);
  const int lane = threadIdx.x & 63;
  const int i = g & 255;
  floatx4 v = *(const floatx4*)(adj + (long long)g * 256 + lane * 4);
  float s = 0.f;
  #pragma unroll
  for (int jj = 0; jj < 4; jj++) {
    const int j = lane * 4 + jj;
    s += (j == i) ? 1.0f : v[jj];
  }
  #pragma unroll
  for (int off = 32; off > 0; off >>= 1) s += __shfl_xor(s, off);
  if (lane == 0) dis[g] = 1.0f / sqrtf(fmaxf(s, 1.0f));
}

// An[b,i,j] = bf16(dis_i * A_ij * dis_j)
__global__ void an_kernel(const float* __restrict__ adj,
                          const float* __restrict__ dis,
                          unsigned short* __restrict__ An)
{
  const long long base = ((long long)blockIdx.x * 256 + threadIdx.x) * 4;
  const int rowg = (int)(base >> 8);
  const int i = rowg & 255;
  const int brow = rowg & ~255;
  const int j0 = (int)(base & 255);
  const float di = dis[rowg];
  floatx4 v = *(const floatx4*)(adj + base);
  ushort4v o;
  #pragma unroll
  for (int jj = 0; jj < 4; jj++) {
    const int j = j0 + jj;
    const float a = (j == i) ? 1.0f : v[jj];
    o[jj] = f2b(di * dis[brow + j] * a);
  }
  *(ushort4v*)(An + base) = o;
}

// ---------------------------------------------------------------------------
// Batched bf16 MFMA GEMM, tile 128x128, BK=128 chunks, 512 threads (8 waves,
// 2x4), each wave 64x32 (acc[4][2]). A (M,K) rm; B (N,K) rm (always NT).
// LDS rows x 16 slots of 16B; slot s holds k-octet q = s ^ (r&7) (XOR swizzle).
// modes:
//  0: f32 store | 1: bf16 store | 2: f32 accumulate | 3: bf16 gelu(val+aux1[col])
//  5: TT store: b=row>>8,n=row&255 -> bf16 C[b*65536+col*256+n]
//  8: final:  f32 C[row*256+col] = gcn[i]+attf[i]+(val+aux1[col])*mask[row]
//  9: GCN epi (C'=U^T): token=zb*256+col, feat=row; g=relu((val+aux1[feat])*mask[token]);
//     bf16 C[token*256+feat]=g; gcn[...] (flag? += : =) g
// 12: f32 C[row*256+col] = gcn[idx] + (val + aux1[col]) * mask[row]
// 13: bf16 store of val * 0.0625  (ABH with attention scale folded)
// 16: V^T scatter only: z2=(row>>8)*8+(col>>8); bf16
//     aux2[z2*65536+(col&255)*256+(row&255)]
// ---------------------------------------------------------------------------
__launch_bounds__(512, 4)
__global__ void gemm_kernel(const unsigned short* __restrict__ A, int lda,
                            long long sAo, long long sAi,
                            const unsigned short* __restrict__ Bm, int ldb,
                            long long sBo, long long sBi,
                            void* __restrict__ Cv, int ldc,
                            long long sCo, long long sCi,
                            int K, int zshift, int mode, int flag,
                            const float* __restrict__ aux1,
                            const float* __restrict__ mask,
                            float* __restrict__ gcn,
                            void* __restrict__ aux2)
{
  __shared__ __align__(16) unsigned short sA[16384];   // 32KB
  __shared__ __align__(16) unsigned short sB[16384];   // 32KB

  const int t = threadIdx.x;
  const int z = blockIdx.z;
  const int zi = z & ((1 << zshift) - 1);
  const int zb = z >> zshift;
  const int m0 = blockIdx.x * 128;
  const int n0 = blockIdx.y * 128;
  A  += zb * sAo + zi * sAi;
  Bm += zb * sBo + zi * sBi;
  const long long cbase = zb * sCo + zi * sCi;

  const int lane = t & 63;
  const int w = t >> 6;              // wave 0..7
  const int wm = w >> 2, wn = w & 3; // 2 x 4
  const int lm = lane & 15, qd = lane >> 4;

  floatx4 acc[4][2] = {};

  const int sub = lane >> 4;        // 0..3
  const int qs  = lane & 15;        // slot within row
  const unsigned short* pA[4];
  const unsigned short* pB[4];
  #pragma unroll
  for (int i = 0; i < 4; i++) {
    const int d = w * 4 + i;        // DMA index 0..31
    const int r = d * 4 + sub;      // tile row 0..127
    const int co = (qs ^ (r & 7)) * 8;   // swizzled col octet (elements)
    pA[i] = A + (long long)(m0 + r) * lda + co;
    pB[i] = Bm + (long long)(n0 + r) * ldb + co;
  }

  for (int kk = 0; kk < K; kk += 128) {
    #pragma unroll
    for (int i = 0; i < 4; i++) {
      gl_lds16(pA[i] + kk, &sA[(w * 4 + i) * 512], lane);
      gl_lds16(pB[i] + kk, &sB[(w * 4 + i) * 512], lane);
    }
    __syncthreads();

    #pragma unroll
    for (int ks = 0; ks < 4; ks++) {
      short8 af[4], bg[2];
      const int q = ks * 4 + qd;          // k-octet 0..15
      #pragma unroll
      for (int mi = 0; mi < 4; mi++) {
        const int r = wm * 64 + mi * 16 + lm;
        af[mi] = *(const short8*)&sA[r * 128 + ((q ^ (r & 7)) * 8)];
      }
      #pragma unroll
      for (int ni = 0; ni < 2; ni++) {
        const int r = wn * 32 + ni * 16 + lm;
        bg[ni] = *(const short8*)&sB[r * 128 + ((q ^ (r & 7)) * 8)];
      }
      #pragma unroll
      for (int mi = 0; mi < 4; mi++)
        #pragma unroll
        for (int ni = 0; ni < 2; ni++)
          acc[mi][ni] = __builtin_amdgcn_mfma_f32_16x16x32_bf16(
              af[mi], bg[ni], acc[mi][ni], 0, 0, 0);
    }
    __syncthreads();
  }

  // ---- epilogue ----
  #pragma unroll
  for (int mi = 0; mi < 4; mi++) {
    const int row0 = m0 + wm * 64 + mi * 16 + qd * 4;
    #pragma unroll
    for (int ni = 0; ni < 2; ni++) {
      const int col = n0 + wn * 32 + ni * 16 + lm;
      floatx4 a = acc[mi][ni];
      if (mode == 0) {
        float* Cf = (float*)Cv;
        #pragma unroll
        for (int r = 0; r < 4; r++)
          Cf[cbase + (long long)(row0 + r) * ldc + col] = a[r];
      } else if (mode == 1) {
        unsigned short* Cb = (unsigned short*)Cv;
        #pragma unroll
        for (int r = 0; r < 4; r++)
          Cb[cbase + (long long)(row0 + r) * ldc + col] = f2b(a[r]);
      } else if (mode == 2) {
        float* Cf = (float*)Cv;
        #pragma unroll
        for (int r = 0; r < 4; r++)
          Cf[cbase + (long long)(row0 + r) * ldc + col] += a[r];
      } else if (mode == 3) {
        unsigned short* Cb = (unsigned short*)Cv;
        const float bv = aux1[col];
        #pragma unroll
        for (int r = 0; r < 4; r++)
          Cb[cbase + (long long)(row0 + r) * ldc + col] = f2b(gelu_f(a[r] + bv));
      } else if (mode == 5) {
        const int b = row0 >> 8, n = row0 & 255;
        ushort4v o;
        #pragma unroll
        for (int r = 0; r < 4; r++) o[r] = f2b(a[r]);
        *(ushort4v*)((unsigned short*)Cv + (long long)b * 65536 + col * 256 + n) = o;
      } else if (mode == 8) {
        float* Cf = (float*)Cv;
        const float* attf = (const float*)aux2;
        const float bv = aux1[col];
        #pragma unroll
        for (int r = 0; r < 4; r++) {
          const long long idx = (long long)(row0 + r) * 256 + col;
          Cf[idx] = gcn[idx] + attf[idx] + (a[r] + bv) * mask[row0 + r];
        }
      } else if (mode == 9) {
        const int token = zb * 256 + col;
        const float m = mask[token];
        ushort4v o; floatx4 g;
        #pragma unroll
        for (int r = 0; r < 4; r++) {
          const float v = fmaxf((a[r] + aux1[row0 + r]) * m, 0.f);
          o[r] = f2b(v); g[r] = v;
        }
        *(ushort4v*)((unsigned short*)Cv + (long long)token * 256 + row0) = o;
        float* gp = gcn + (long long)token * 256 + row0;
        if (flag) { floatx4 old = *(const floatx4*)gp; g += old; }
        *(floatx4*)gp = g;
      } else if (mode == 12) { // U = GCN + (val + bo)*mask
        float* Cf = (float*)Cv;
        const float bv = aux1[col];
        #pragma unroll
        for (int r = 0; r < 4; r++) {
          const long long idx = (long long)(row0 + r) * 256 + col;
          Cf[idx] = gcn[idx] + (a[r] + bv) * mask[row0 + r];
        }
      } else if (mode == 13) { // scaled bf16 (ABH /16)
        unsigned short* Cb = (unsigned short*)Cv;
        #pragma unroll
        for (int r = 0; r < 4; r++)
          Cb[cbase + (long long)(row0 + r) * ldc + col] = f2b(a[r] * 0.0625f);
      } else { // 16: V^T scatter only (col = h*256 + e)
        const int z2 = (row0 >> 8) * 8 + (col >> 8);
        const int e = col & 255, n = row0 & 255;
        ushort4v o;
        #pragma unroll
        for (int r = 0; r < 4; r++) o[r] = f2b(a[r]);
        *(ushort4v*)((unsigned short*)aux2 + (long long)z2 * 65536 + e * 256 + n) = o;
      }
    }
  }
}

// ---------------------------------------------------------------------------
// Fused attention v11 (= v10 + whole-b XCD grouping):
//  * v10's mapping put the 4 mt-siblings of one (b,h) on 4 DIFFERENT XCDs,
//    so V^T (the largest per-block stream, shared only by mt-siblings) was
//    fetched ~4x from HBM (FETCH 175 MB vs ~85 MB unique) and chunk loads
//    were HBM-latency (~900cy) — beyond the 1-iteration vmcnt lookahead.
//  * v11: XCD x owns whole b's (b = x, x+8, ..., x+56); within a b the 32
//    blocks order mt-fastest, then h.  Per-XCD working set while one b is
//    live = V(1 MB) + H(128 KB) + dist(128 KB) + ABH(1 MB) < 4 MB L2 ->
//    every stream fetched ONCE from HBM; chunk loads become L2 hits
//    (~200cy), which one compute phase fully covers.
//  * Everything else identical to v10 (continuous staging ledger, 2-deep
//    counted vmcnt, raw s_barrier, sR0 time-sharing, 68.6 KB LDS,
//    2 blocks/CU).
// ---------------------------------------------------------------------------
__launch_bounds__(512, 4)
__global__ void attn_kernel(unsigned short* __restrict__ QP,   // (16384,2048) Y out
                            const unsigned short* __restrict__ HBF, // (16384,256)
                            const unsigned short* __restrict__ ABH, // (2048,256)
                            const unsigned short* __restrict__ VT,  // (512,256,256)
                            const unsigned short* __restrict__ DSTB,// (64,256,256) bf16
                            const float* __restrict__ mask)
{
  __shared__ __align__(16) unsigned short sR0[16896];  // 33KB: Hq -> Q' -> P -> Yepi
  __shared__ __align__(16) unsigned short sS[16384];   // 32KB: 2 x 16KB stream bufs
  __shared__ float redm[4][64];
  __shared__ float reds[4][64];

  // whole-b XCD grouping: XCD x (= bi&7 under round-robin dispatch) owns
  // b in {x, x+8, ..., x+56}; within b, mt varies fastest (V_z stays hot),
  // then h (H_b/dist stay hot across all 32 blocks of the b).
  const int bi = blockIdx.x;              // 0..2047
  const int x  = bi & 7;
  const int seq = bi >> 3;                // 0..255 within XCD
  const int b  = (seq >> 5) * 8 + x;      // 8 b's per XCD
  const int h  = (seq >> 2) & 7;
  const int mt = seq & 3;
  const int m0 = mt * 64;
  const int z = b * 8 + h;

  const int t = threadIdx.x, lane = t & 63, w = t >> 6;
  const int lm = lane & 15, qd = lane >> 4;
  const int wm2 = w >> 2, wn4 = w & 3;    // 2 row-groups x 4 key/e-groups

  unsigned short* Ym = QP + ((long long)(b * 256 + m0)) * 2048 + h * 256;
  const unsigned short* Hb = HBF + (long long)b * 65536;
  const unsigned short* Hq = Hb + (long long)m0 * 256;
  const unsigned short* Ah = ABH + (long long)h * 65536;
  const unsigned short* Vb = VT + (long long)z * 65536;
  const unsigned short* db = DSTB + (long long)b * 65536 + (long long)m0 * 256;
  const float* maskb = mask + b * 256;

  // ---- dist preload (oldest vmem ops; compiler auto-waits before first
  //      use; becomes the S-phase MFMA C-in, folding "+dist" into MFMA) ----
  floatx4 S[2][4];
  #pragma unroll
  for (int mi = 0; mi < 2; mi++)
    #pragma unroll
    for (int ni = 0; ni < 4; ni++) {
      const int col = wn4 * 64 + ni * 16 + lm;
      #pragma unroll
      for (int r = 0; r < 4; r++) {
        const int row = wm2 * 32 + mi * 16 + qd * 4 + r;
        S[mi][ni][r] = b2f(db[row * 256 + col]);
      }
    }

  // ---- per-thread staging geometry (all 24 chunks: 256 rows x 64 B) ----
  int eoff0, eoff1;
  {
    const int rA = lane >> 2, sl = lane & 3;
    const int r0 = (w * 2 + 0) * 16 + rA;
    const int r1 = (w * 2 + 1) * 16 + rA;
    eoff0 = r0 * 256 + ((sl ^ ((r0 >> 1) & 3)) * 8);
    eoff1 = r1 * 256 + ((sl ^ ((r1 >> 1) & 3)) * 8);
  }
  const int ld0 = (w * 2 + 0) * 512;
  const int ld1 = (w * 2 + 1) * 512;

  auto STAGE = [&](int c) {
    const unsigned short* bp =
        (c < 8 ? Ah : (c < 16 ? Hb : Vb)) + (c & 7) * 32;
    const int bb = (c & 1) * 8192;
    gl_lds16(bp + eoff0, &sS[bb + ld0], lane);
    gl_lds16(bp + eoff1, &sS[bb + ld1], lane);
  };

  // ---- prologue: H_q tile (32 KB -> sR0) + chunks 0,1 ----
  {
    const int rin2 = lane >> 5, qs32 = lane & 31;
    #pragma unroll
    for (int i = 0; i < 4; i++) {
      const int d = w * 4 + i;
      const int r = d * 2 + rin2;          // H_q row 0..63
      gl_lds16(Hq + (long long)r * 256 + ((qs32 ^ (r & 7)) * 8),
               &sR0[d * 512], lane);
    }
  }
  STAGE(0); STAGE(1);
  VMW2();                                  // dist + H_q + chunk0 retired
  MBAR();

  // ---- phase 1: Q' = H_q * ABH_h^T  (chunks 0..7) ----
  floatx4 accq[2][4] = {};
  #pragma unroll
  for (int c = 0; c < 8; c++) {
    __builtin_amdgcn_s_setprio(1);
    short8 af[2], bg[4];
    #pragma unroll
    for (int mi = 0; mi < 2; mi++) {
      const int r = wm2 * 32 + mi * 16 + lm;
      const int q = c * 4 + qd;
      af[mi] = *(const short8*)&sR0[r * 256 + ((q ^ (r & 7)) * 8)];
    }
    const int bb = (c & 1) * 8192;
    #pragma unroll
    for (int ni = 0; ni < 4; ni++) {
      const int rr = wn4 * 64 + ni * 16 + lm;
      bg[ni] = *(const short8*)&sS[bb + rr * 32 + ((qd ^ ((rr >> 1) & 3)) * 8)];
    }
    #pragma unroll
    for (int mi = 0; mi < 2; mi++)
      #pragma unroll
      for (int ni = 0; ni < 4; ni++)
        accq[mi][ni] = __builtin_amdgcn_mfma_f32_16x16x32_bf16(
            af[mi], bg[ni], accq[mi][ni], 0, 0, 0);
    __builtin_amdgcn_s_setprio(0);
    MBAR();                                // all waves done with buf c&1
    STAGE(c + 2);                          // chunks 2..9 (continuous)
    VMW2();                                // chunk c+1 retired
    MBAR();
  }

  // ---- transition: materialize Q' bf16 into sR0 (chunks 8,9 in flight) ----
  #pragma unroll
  for (int mi = 0; mi < 2; mi++)
    #pragma unroll
    for (int rr = 0; rr < 4; rr++) {
      const int row = wm2 * 32 + mi * 16 + qd * 4 + rr;
      #pragma unroll
      for (int ni = 0; ni < 4; ni++) {
        const int col = wn4 * 64 + ni * 16 + lm;
        const int o = col >> 3;
        sR0[row * 256 + ((o ^ (row & 7)) * 8) + (col & 7)] = f2b(accq[mi][ni][rr]);
      }
    }
  LGW0();
  MBAR();                                  // Q' visible to all waves

  // ---- phase 2: S = Q' * H^T + dist  (chunks 8..15) ----
  #pragma unroll
  for (int c = 8; c < 16; c++) {
    __builtin_amdgcn_s_setprio(1);
    short8 af[2], bg[4];
    #pragma unroll
    for (int mi = 0; mi < 2; mi++) {
      const int r = wm2 * 32 + mi * 16 + lm;
      const int q = (c - 8) * 4 + qd;
      af[mi] = *(const short8*)&sR0[r * 256 + ((q ^ (r & 7)) * 8)];
    }
    const int bb = (c & 1) * 8192;
    #pragma unroll
    for (int ni = 0; ni < 4; ni++) {
      const int rr = wn4 * 64 + ni * 16 + lm;
      bg[ni] = *(const short8*)&sS[bb + rr * 32 + ((qd ^ ((rr >> 1) & 3)) * 8)];
    }
    #pragma unroll
    for (int mi = 0; mi < 2; mi++)
      #pragma unroll
      for (int ni = 0; ni < 4; ni++)
        S[mi][ni] = __builtin_amdgcn_mfma_f32_16x16x32_bf16(
            af[mi], bg[ni], S[mi][ni], 0, 0, 0);
    __builtin_amdgcn_s_setprio(0);
    MBAR();
    STAGE(c + 2);                          // chunks 10..17 (continuous)
    VMW2();
    MBAR();
  }

  // ---- transition: softmax; P planes into sR0 (chunks 16,17 staged) ----
  float mkv[4];
  #pragma unroll
  for (int ni = 0; ni < 4; ni++) mkv[ni] = maskb[wn4 * 64 + ni * 16 + lm];

  float lred[2][4];
  #pragma unroll
  for (int mi = 0; mi < 2; mi++) {
    #pragma unroll
    for (int r = 0; r < 4; r++) {
      const int row = wm2 * 32 + mi * 16 + qd * 4 + r;
      const float mq = maskb[m0 + row];
      float mx = -3e38f;
      #pragma unroll
      for (int ni = 0; ni < 4; ni++) {
        const float v = (mq != 0.f && mkv[ni] != 0.f) ? S[mi][ni][r] : -1e9f;
        S[mi][ni][r] = v;
        mx = fmaxf(mx, v);
      }
      lred[mi][r] = mx;
    }
  }
  #pragma unroll
  for (int off = 1; off < 16; off <<= 1)
    #pragma unroll
    for (int mi = 0; mi < 2; mi++)
      #pragma unroll
      for (int r = 0; r < 4; r++)
        lred[mi][r] = fmaxf(lred[mi][r], __shfl_xor(lred[mi][r], off));
  if (lm == 0)
    #pragma unroll
    for (int mi = 0; mi < 2; mi++)
      #pragma unroll
      for (int r = 0; r < 4; r++)
        redm[wn4][wm2 * 32 + mi * 16 + qd * 4 + r] = lred[mi][r];
  LGW0();
  MBAR();

  #pragma unroll
  for (int mi = 0; mi < 2; mi++) {
    #pragma unroll
    for (int r = 0; r < 4; r++) {
      const int row = wm2 * 32 + mi * 16 + qd * 4 + r;
      const float gmax = fmaxf(fmaxf(redm[0][row], redm[1][row]),
                               fmaxf(redm[2][row], redm[3][row]));
      float ss = 0.f;
      #pragma unroll
      for (int ni = 0; ni < 4; ni++) {
        const float e = __expf(S[mi][ni][r] - gmax);   // invalid -> exactly 0
        S[mi][ni][r] = e;
        ss += e;
      }
      lred[mi][r] = ss;
    }
  }
  #pragma unroll
  for (int off = 1; off < 16; off <<= 1)
    #pragma unroll
    for (int mi = 0; mi < 2; mi++)
      #pragma unroll
      for (int r = 0; r < 4; r++)
        lred[mi][r] += __shfl_xor(lred[mi][r], off);
  if (lm == 0)
    #pragma unroll
    for (int mi = 0; mi < 2; mi++)
      #pragma unroll
      for (int r = 0; r < 4; r++)
        reds[wn4][wm2 * 32 + mi * 16 + qd * 4 + r] = lred[mi][r];
  LGW0();
  MBAR();

  // normalize; P planes [wn4][64 rows][64 keys] (128B rows; overwrites Q')
  #pragma unroll
  for (int mi = 0; mi < 2; mi++)
    #pragma unroll
    for (int r = 0; r < 4; r++) {
      const int row = wm2 * 32 + mi * 16 + qd * 4 + r;
      const float inv = 1.0f / (reds[0][row] + reds[1][row] +
                                reds[2][row] + reds[3][row]);
      #pragma unroll
      for (int ni = 0; ni < 4; ni++) {
        const int kl = ni * 16 + lm;
        const int slot = (kl >> 3) ^ (row & 7);
        sR0[wn4 * 4096 + row * 64 + slot * 8 + (kl & 7)] =
            f2b(S[mi][ni][r] * inv);
      }
    }
  LGW0();
  MBAR();                                  // P visible

  // ---- phase 3: Y = P * V  (chunks 16..23) ----
  floatx4 Y[2][4] = {};
  #pragma unroll
  for (int c = 16; c < 24; c++) {
    __builtin_amdgcn_s_setprio(1);
    const int pp = (c - 16) >> 1;
    const int op = ((c - 16) & 1) * 4 + qd;
    short8 af[2], bg[4];
    #pragma unroll
    for (int mi = 0; mi < 2; mi++) {
      const int r = wm2 * 32 + mi * 16 + lm;
      af[mi] = *(const short8*)&sR0[pp * 4096 + r * 64 + ((op ^ (r & 7)) * 8)];
    }
    const int bb = (c & 1) * 8192;
    #pragma unroll
    for (int ni = 0; ni < 4; ni++) {
      const int rr = wn4 * 64 + ni * 16 + lm;
      bg[ni] = *(const short8*)&sS[bb + rr * 32 + ((qd ^ ((rr >> 1) & 3)) * 8)];
    }
    #pragma unroll
    for (int mi = 0; mi < 2; mi++)
      #pragma unroll
      for (int ni = 0; ni < 4; ni++)
        Y[mi][ni] = __builtin_amdgcn_mfma_f32_16x16x32_bf16(
            af[mi], bg[ni], Y[mi][ni], 0, 0, 0);
    __builtin_amdgcn_s_setprio(0);
    MBAR();
    if (c < 22) {
      STAGE(c + 2);                        // chunks 18..23
      VMW2();
      MBAR();
    } else if (c == 22) {
      VMW0();                              // drain chunk 23 (no prefetch left)
      MBAR();
    }
  }

  // ---- epilogue: Y -> sR0 (stride 264) -> 16B coalesced stores ----
  #pragma unroll
  for (int mi = 0; mi < 2; mi++)
    #pragma unroll
    for (int ni = 0; ni < 4; ni++) {
      const int col = wn4 * 64 + ni * 16 + lm;
      #pragma unroll
      for (int r = 0; r < 4; r++) {
        const int rl = wm2 * 32 + mi * 16 + qd * 4 + r;   // 0..63
        sR0[rl * 264 + col] = f2b(Y[mi][ni][r]);
      }
    }
  LGW0();
  MBAR();
  #pragma unroll
  for (int it = 0; it < 4; it++) {
    const int idx = it * 512 + t;          // 0..2047 = 64 rows x 32 x 16B
    const int row = idx >> 5, u = idx & 31;
    short8 v = *(const short8*)&sR0[row * 264 + u * 8];
    *(short8*)(Ym + (long long)row * 2048 + u * 8) = v;
  }
}

// ---------------------------------------------------------------------------
__global__ void ln_kernel(const float* __restrict__ X,
                          const float* __restrict__ gam,
                          const float* __restrict__ bet,
                          unsigned short* __restrict__ out)
{
  const int g = blockIdx.x * 4 + (threadIdx.x >> 6);
  const int lane = threadIdx.x & 63;
  floatx4 v = *(const floatx4*)(X + (long long)g * 256 + lane * 4);
  float s = v[0] + v[1] + v[2] + v[3];
  float sq = v[0]*v[0] + v[1]*v[1] + v[2]*v[2] + v[3]*v[3];
  #pragma unroll
  for (int off = 32; off > 0; off >>= 1) {
    s  += __shfl_xor(s, off);
    sq += __shfl_xor(sq, off);
  }
  const float mean = s * (1.0f / 256.0f);
  const float var = sq * (1.0f / 256.0f) - mean * mean;
  const float rs = 1.0f / sqrtf(var + 1e-5f);
  ushort4v o;
  #pragma unroll
  for (int jj = 0; jj < 4; jj++) {
    const int c = lane * 4 + jj;
    o[jj] = f2b((v[jj] - mean) * rs * gam[c] + bet[c]);
  }
  *(ushort4v*)(out + (long long)g * 256 + lane * 4) = o;
}

// ---------------------------------------------------------------------------
static inline void launch_gemm(hipStream_t st, int M, int N, int batch,
    const void* A, int lda, long long sAo, long long sAi,
    const void* B, int ldb, long long sBo, long long sBi,
    void* C, int ldc, long long sCo, long long sCi,
    int K, int zshift, int mode, int flag,
    const float* aux1, const float* mask, float* gcn, void* aux2)
{
  dim3 grid(M / 128, N / 128, batch), blk(512);
  gemm_kernel<<<grid, blk, 0, st>>>(
      (const unsigned short*)A, lda, sAo, sAi,
      (const unsigned short*)B, ldb, sBo, sBi,
      C, ldc, sCo, sCi, K, zshift, mode, flag, aux1, mask, gcn, aux2);
}

extern "C" void kernel_launch(void* const* d_in, const int* in_sizes, int n_in,
                              void* d_out, int out_size, void* d_ws, size_t ws_size,
                              hipStream_t stream)
{
  (void)in_sizes; (void)n_in; (void)out_size;
  const float* x    = (const float*)d_in[0];
  const float* adj  = (const float*)d_in[1];
  const float* mask = (const float*)d_in[2];
  const float* dist = (const float*)d_in[3];
  const float* W1   = (const float*)d_in[4];
  const float* b1   = (const float*)d_in[5];
  const float* W2   = (const float*)d_in[6];
  const float* b2   = (const float*)d_in[7];
  const float* W3   = (const float*)d_in[8];
  const float* b3   = (const float*)d_in[9];
  const float* ln1g = (const float*)d_in[10];
  const float* ln1b = (const float*)d_in[11];
  const float* Wq   = (const float*)d_in[12];
  const float* Wk   = (const float*)d_in[13];
  const float* Wv   = (const float*)d_in[14];
  const float* Wo   = (const float*)d_in[15];
  const float* bo   = (const float*)d_in[16];
  const float* ln2g = (const float*)d_in[17];
  const float* ln2b = (const float*)d_in[18];
  const float* Wf1  = (const float*)d_in[19];
  const float* bf1  = (const float*)d_in[20];
  const float* Wf2  = (const float*)d_in[21];
  const float* bf2  = (const float*)d_in[22];

  char* w = (char*)d_ws;
  auto alloc = [&](size_t sz) { void* p = (void*)w; w += sz; return p; };
  // persistent (~61 MB)
  unsigned short* W1T   = (unsigned short*)alloc(65536);      // (256,128)
  unsigned short* W2T   = (unsigned short*)alloc(131072);     // (256,256)
  unsigned short* W3T   = (unsigned short*)alloc(131072);
  unsigned short* ABH   = (unsigned short*)alloc(1048576);    // (2048,256) = Wk_h Wq_h^T /16
  unsigned short* WVT   = (unsigned short*)alloc(1048576);    // (2048,256)
  unsigned short* WOT   = (unsigned short*)alloc(1048576);    // (256,2048)
  unsigned short* WF1T  = (unsigned short*)alloc(524288);     // (1024,256)
  unsigned short* WF2T  = (unsigned short*)alloc(524288);     // (256,1024)
  unsigned short* WQb   = (unsigned short*)alloc(1048576);    // (256,2048) plain
  unsigned short* WKb   = (unsigned short*)alloc(1048576);    // (256,2048) plain
  unsigned short* XBF   = (unsigned short*)alloc(4194304);    // (16384,128)
  unsigned short* DSTB  = (unsigned short*)alloc(8388608);    // (64,256,256) bf16 dist
  float*          GCN   = (float*)         alloc(16777216);   // (16384,256)
  float*          U     = (float*)         alloc(16777216);   // ATT f32
  unsigned short* HBF   = (unsigned short*)alloc(8388608);    // (16384,256)
  float*          DIS   = (float*)         alloc(65536);
  // scratch union (peak = attention: 134.2 MB)
  char* scratch = (char*)alloc(134217728);
  if ((size_t)(w - (char*)d_ws) > ws_size) return;
  // gcn phase views
  unsigned short* AN  = (unsigned short*)scratch;              // 8.4 MB
  unsigned short* TT  = (unsigned short*)(scratch + 8388608);  // 8.4 MB
  unsigned short* GBF = (unsigned short*)(scratch + 16777216); // 8.4 MB
  // attention phase views
  unsigned short* QPB = (unsigned short*)scratch;                 // (16384,2048) 67 MB  Y
  unsigned short* VT  = (unsigned short*)(scratch + 67108864);    // (512,256,256) 67 MB
  // ffn phase view
  unsigned short* FFB = (unsigned short*)scratch;                 // 33.6 MB

  // ---- single packing launch: 7 transposes + 4 plain cvts ----
  PackArgs pa;
  const float* srcs[11] = {W1, W2, W3, Wv, Wo, Wf1, Wf2, x, Wq, Wk, dist};
  unsigned short* dsts[11] = {W1T, W2T, W3T, WVT, WOT, WF1T, WF2T, XBF, WQb, WKb, DSTB};
  const int Rs[11] = {128, 256, 256, 256, 2048, 256, 1024,
                      BNROWS * INF_, EE * HH * EE, EE * HH * EE, BB * 65536};
  const int Cs[11] = {256, 256, 256, 2048, 256, 1024, 256, 0, 0, 0, 0};
  const int sts[12] = {0, 32, 96, 160, 672, 1184, 1440, 1696, 3744, 4256, 4768, 8864};
  for (int j = 0; j < 11; j++) {
    pa.src[j] = srcs[j]; pa.dst[j] = dsts[j]; pa.R[j] = Rs[j]; pa.C[j] = Cs[j];
  }
  for (int j = 0; j < 12; j++) pa.start[j] = sts[j];
  pack_kernel<<<8864, 256, 0, stream>>>(pa);

  // ---- adjacency normalization ----
  deg_kernel<<<4096, 256, 0, stream>>>(adj, DIS);
  an_kernel<<<4096, 256, 0, stream>>>(adj, DIS, AN);

  // ---- ABH_h = Wk_h Wq_h^T / 16  (8 heads, tiny batched GEMM) ----
  launch_gemm(stream, 256, 256, 8, WKb, 2048, 256, 0, WQb, 2048, 256, 0,
              ABH, 256, 65536, 0, 256, 0, 13, 0, nullptr, nullptr, nullptr, nullptr);

  // ---- GCN stack ----
  launch_gemm(stream, BNROWS, EE, 1, XBF, 128, 0,0, W1T, 128, 0,0,
              TT, 256, 0,0, 128, 0, 5, 0, nullptr, nullptr, nullptr, nullptr);
  launch_gemm(stream, 256, 256, BB, TT, 256, 65536,0, AN, 256, 65536,0,
              GBF, 256, 0,0, 256, 0, 9, 0, b1, mask, GCN, nullptr);
  launch_gemm(stream, BNROWS, EE, 1, GBF, 256, 0,0, W2T, 256, 0,0,
              TT, 256, 0,0, 256, 0, 5, 0, nullptr, nullptr, nullptr, nullptr);
  launch_gemm(stream, 256, 256, BB, TT, 256, 65536,0, AN, 256, 65536,0,
              GBF, 256, 0,0, 256, 0, 9, 1, b2, mask, GCN, nullptr);
  launch_gemm(stream, BNROWS, EE, 1, GBF, 256, 0,0, W3T, 256, 0,0,
              TT, 256, 0,0, 256, 0, 5, 0, nullptr, nullptr, nullptr, nullptr);
  launch_gemm(stream, 256, 256, BB, TT, 256, 65536,0, AN, 256, 65536,0,
              GBF, 256, 0,0, 256, 0, 9, 1, b3, mask, GCN, nullptr);

  // ---- LN1 ----
  ln_kernel<<<4096, 256, 0, stream>>>(GCN, ln1g, ln1b, HBF);

  // ---- attention: V^T GEMM -> fused attn (Q' in-kernel) -> Y@Wo ----
  launch_gemm(stream, BNROWS, 2048, 1, HBF, 256, 0,0, WVT, 256, 0,0,
              QPB, 2048, 0,0, 256, 0, 16, 0, nullptr, nullptr, nullptr, VT);
  attn_kernel<<<2048, 512, 0, stream>>>(QPB, HBF, ABH, VT, DSTB, mask);
  launch_gemm(stream, BNROWS, EE, 1, QPB, 2048, 0,0, WOT, 2048, 0,0,
              U, 256, 0,0, 2048, 0, 12, 0, bo, mask, GCN, nullptr);

  // ---- LN2 + FFN (final residual fused into FFN2 epilogue) ----
  ln_kernel<<<4096, 256, 0, stream>>>(U, ln2g, ln2b, HBF);
  launch_gemm(stream, BNROWS, FFN, 1, HBF, 256, 0,0, WF1T, 256, 0,0,
              FFB, 1024, 0,0, 256, 0, 3, 0, bf1, nullptr, nullptr, nullptr);
  launch_gemm(stream, BNROWS, EE, 1, FFB, 1024, 0,0, WF2T, 1024, 0,0,
              d_out, 256, 0,0, 1024, 0, 8, 0, bf2, mask, GCN, U);
}

// Round 7
// 449.648 us; speedup vs baseline: 1.1048x; 1.0082x over previous
//
#include <hip/hip_runtime.h>
#include <hip/hip_bf16.h>
#include <cmath>

// Problem constants: B=64, N=256, IN=128, E=256, H=8, F=1024
#define BB 64
#define NNODES 256
#define INF_ 128
#define EE 256
#define HH 8
#define FFN 1024
#define BNROWS 16384   // B*N

typedef __attribute__((ext_vector_type(8))) short short8;
typedef __attribute__((ext_vector_type(4))) float floatx4;
typedef __attribute__((ext_vector_type(4))) unsigned short ushort4v;

__device__ __forceinline__ float b2f(unsigned short u) {
  union { unsigned u32; float f; } w; w.u32 = ((unsigned)u) << 16; return w.f;
}
__device__ __forceinline__ unsigned short f2b(float f) {
  union { float f; unsigned u32; } w; w.f = f;
  unsigned r = w.u32 + 0x7FFFu + ((w.u32 >> 16) & 1u);   // RNE
  return (unsigned short)(r >> 16);
}
// tanh-gelu (max abs dev from exact erf-gelu ~3e-4, far below bf16 rounding)
__device__ __forceinline__ float gelu_f(float x) {
  const float z = 0.7978845608028654f * (x + 0.044715f * x * x * x);
  const float e = __expf(2.0f * z);
  const float th = (e - 1.0f) / (e + 1.0f);
  return 0.5f * x * (1.0f + th);
}

typedef const __attribute__((address_space(1))) void GV;
typedef __attribute__((address_space(3))) void LV;

// async global->LDS: per-lane 16B source, wave-uniform LDS base (+lane*16)
__device__ __forceinline__ void gl_lds16(const unsigned short* g,
                                         unsigned short* l, int lane) {
#if __has_builtin(__builtin_amdgcn_global_load_lds)
  __builtin_amdgcn_global_load_lds((GV*)g, (LV*)l, 16, 0, 0);
#else
  *(short8*)(l + lane * 8) = *(const short8*)g;
#endif
}

#define VMW2() asm volatile("s_waitcnt vmcnt(2)" ::: "memory")
#define VMW0() asm volatile("s_waitcnt vmcnt(0)" ::: "memory")
#define LGW0() asm volatile("s_waitcnt lgkmcnt(0)" ::: "memory")
#define MBAR() do { asm volatile("" ::: "memory"); \
                    __builtin_amdgcn_s_barrier(); \
                    asm volatile("" ::: "memory"); } while (0)

// ---------------------------------------------------------------------------
// One kernel for ALL packing: transpose-cvt jobs + plain cvt jobs (C==0).
// ---------------------------------------------------------------------------
struct PackArgs {
  const float* src[12];
  unsigned short* dst[12];
  int R[12], C[12];
  int start[13];
};

__launch_bounds__(256)
__global__ void pack_kernel(PackArgs a)
{
  __shared__ float tile[32][33];
  const int bid = blockIdx.x;
  int j = 0;
  while (bid >= a.start[j + 1]) j++;
  const int lb = bid - a.start[j];
  const float* src = a.src[j];
  unsigned short* dst = a.dst[j];
  const int R = a.R[j], C = a.C[j];

  if (C == 0) {      // plain cvt, R = element count
    const int i = (lb * 256 + threadIdx.x) * 4;
    if (i >= R) return;
    floatx4 v = *(const floatx4*)(src + i);
    ushort4v o;
    #pragma unroll
    for (int k = 0; k < 4; k++) o[k] = f2b(v[k]);
    *(ushort4v*)(dst + i) = o;
    return;
  }
  const int tpr = C >> 5;
  const int c0 = (lb % tpr) * 32, r0 = (lb / tpr) * 32;
  const int tx = threadIdx.x & 31, ty = threadIdx.x >> 5;
  #pragma unroll
  for (int i = ty; i < 32; i += 8)
    tile[i][tx] = src[(long long)(r0 + i) * C + c0 + tx];
  __syncthreads();
  #pragma unroll
  for (int i = ty; i < 32; i += 8)
    dst[(long long)(c0 + i) * R + r0 + tx] = f2b(tile[tx][i]);
}

// ---------------------------------------------------------------------------
// dis = rsqrt(clip(rowsum(A),1,inf)); A = adj (f32) with diag forced to 1
// ---------------------------------------------------------------------------
__global__ void deg_kernel(const float* __restrict__ adj,
                           float* __restrict__ dis)
{
  const int g = blockIdx.x * 4 + (threadIdx.x >> 6);
  const int lane = threadIdx.x & 63;
  const int i = g & 255;
  floatx4 v = *(const floatx4*)(adj + (long long)g * 256 + lane * 4);
  float s = 0.f;
  #pragma unroll
  for (int jj = 0; jj < 4; jj++) {
    const int j = lane * 4 + jj;
    s += (j == i) ? 1.0f : v[jj];
  }
  #pragma unroll
  for (int off = 32; off > 0; off >>= 1) s += __shfl_xor(s, off);
  if (lane == 0) dis[g] = 1.0f / sqrtf(fmaxf(s, 1.0f));
}

// An[b,i,j] = bf16(dis_i * A_ij * dis_j)
__global__ void an_kernel(const float* __restrict__ adj,
                          const float* __restrict__ dis,
                          unsigned short* __restrict__ An)
{
  const long long base = ((long long)blockIdx.x * 256 + threadIdx.x) * 4;
  const int rowg = (int)(base >> 8);
  const int i = rowg & 255;
  const int brow = rowg & ~255;
  const int j0 = (int)(base & 255);
  const float di = dis[rowg];
  floatx4 v = *(const floatx4*)(adj + base);
  ushort4v o;
  #pragma unroll
  for (int jj = 0; jj < 4; jj++) {
    const int j = j0 + jj;
    const float a = (j == i) ? 1.0f : v[jj];
    o[jj] = f2b(di * dis[brow + j] * a);
  }
  *(ushort4v*)(An + base) = o;
}

// ---------------------------------------------------------------------------
// Batched bf16 MFMA GEMM, tile 128x128, BK=128 chunks, 512 threads (8 waves,
// 2x4), each wave 64x32 (acc[4][2]). A (M,K) rm; B (N,K) rm (always NT).
// LDS rows x 16 slots of 16B; slot s holds k-octet q = s ^ (r&7) (XOR swizzle).
// modes:
//  0: f32 store | 1: bf16 store | 2: f32 accumulate | 3: bf16 gelu(val+aux1[col])
//  5: TT store: b=row>>8,n=row&255 -> bf16 C[b*65536+col*256+n]
//  8: final:  f32 C[row*256+col] = gcn[i]+attf[i]+(val+aux1[col])*mask[row]
//  9: GCN epi (C'=U^T): token=zb*256+col, feat=row; g=relu((val+aux1[feat])*mask[token]);
//     bf16 C[token*256+feat]=g; gcn[...] (flag? += : =) g
// 12: f32 C[row*256+col] = gcn[idx] + (val + aux1[col]) * mask[row]
// 13: bf16 store of val * 0.0625  (ABH with attention scale folded)
// 16: V^T scatter only: z2=(row>>8)*8+(col>>8); bf16
//     aux2[z2*65536+(col&255)*256+(row&255)]
// ---------------------------------------------------------------------------
__launch_bounds__(512, 4)
__global__ void gemm_kernel(const unsigned short* __restrict__ A, int lda,
                            long long sAo, long long sAi,
                            const unsigned short* __restrict__ Bm, int ldb,
                            long long sBo, long long sBi,
                            void* __restrict__ Cv, int ldc,
                            long long sCo, long long sCi,
                            int K, int zshift, int mode, int flag,
                            const float* __restrict__ aux1,
                            const float* __restrict__ mask,
                            float* __restrict__ gcn,
                            void* __restrict__ aux2)
{
  __shared__ __align__(16) unsigned short sA[16384];   // 32KB
  __shared__ __align__(16) unsigned short sB[16384];   // 32KB

  const int t = threadIdx.x;
  const int z = blockIdx.z;
  const int zi = z & ((1 << zshift) - 1);
  const int zb = z >> zshift;
  const int m0 = blockIdx.x * 128;
  const int n0 = blockIdx.y * 128;
  A  += zb * sAo + zi * sAi;
  Bm += zb * sBo + zi * sBi;
  const long long cbase = zb * sCo + zi * sCi;

  const int lane = t & 63;
  const int w = t >> 6;              // wave 0..7
  const int wm = w >> 2, wn = w & 3; // 2 x 4
  const int lm = lane & 15, qd = lane >> 4;

  floatx4 acc[4][2] = {};

  const int sub = lane >> 4;        // 0..3
  const int qs  = lane & 15;        // slot within row
  const unsigned short* pA[4];
  const unsigned short* pB[4];
  #pragma unroll
  for (int i = 0; i < 4; i++) {
    const int d = w * 4 + i;        // DMA index 0..31
    const int r = d * 4 + sub;      // tile row 0..127
    const int co = (qs ^ (r & 7)) * 8;   // swizzled col octet (elements)
    pA[i] = A + (long long)(m0 + r) * lda + co;
    pB[i] = Bm + (long long)(n0 + r) * ldb + co;
  }

  for (int kk = 0; kk < K; kk += 128) {
    #pragma unroll
    for (int i = 0; i < 4; i++) {
      gl_lds16(pA[i] + kk, &sA[(w * 4 + i) * 512], lane);
      gl_lds16(pB[i] + kk, &sB[(w * 4 + i) * 512], lane);
    }
    __syncthreads();

    #pragma unroll
    for (int ks = 0; ks < 4; ks++) {
      short8 af[4], bg[2];
      const int q = ks * 4 + qd;          // k-octet 0..15
      #pragma unroll
      for (int mi = 0; mi < 4; mi++) {
        const int r = wm * 64 + mi * 16 + lm;
        af[mi] = *(const short8*)&sA[r * 128 + ((q ^ (r & 7)) * 8)];
      }
      #pragma unroll
      for (int ni = 0; ni < 2; ni++) {
        const int r = wn * 32 + ni * 16 + lm;
        bg[ni] = *(const short8*)&sB[r * 128 + ((q ^ (r & 7)) * 8)];
      }
      #pragma unroll
      for (int mi = 0; mi < 4; mi++)
        #pragma unroll
        for (int ni = 0; ni < 2; ni++)
          acc[mi][ni] = __builtin_amdgcn_mfma_f32_16x16x32_bf16(
              af[mi], bg[ni], acc[mi][ni], 0, 0, 0);
    }
    __syncthreads();
  }

  // ---- epilogue ----
  #pragma unroll
  for (int mi = 0; mi < 4; mi++) {
    const int row0 = m0 + wm * 64 + mi * 16 + qd * 4;
    #pragma unroll
    for (int ni = 0; ni < 2; ni++) {
      const int col = n0 + wn * 32 + ni * 16 + lm;
      floatx4 a = acc[mi][ni];
      if (mode == 0) {
        float* Cf = (float*)Cv;
        #pragma unroll
        for (int r = 0; r < 4; r++)
          Cf[cbase + (long long)(row0 + r) * ldc + col] = a[r];
      } else if (mode == 1) {
        unsigned short* Cb = (unsigned short*)Cv;
        #pragma unroll
        for (int r = 0; r < 4; r++)
          Cb[cbase + (long long)(row0 + r) * ldc + col] = f2b(a[r]);
      } else if (mode == 2) {
        float* Cf = (float*)Cv;
        #pragma unroll
        for (int r = 0; r < 4; r++)
          Cf[cbase + (long long)(row0 + r) * ldc + col] += a[r];
      } else if (mode == 3) {
        unsigned short* Cb = (unsigned short*)Cv;
        const float bv = aux1[col];
        #pragma unroll
        for (int r = 0; r < 4; r++)
          Cb[cbase + (long long)(row0 + r) * ldc + col] = f2b(gelu_f(a[r] + bv));
      } else if (mode == 5) {
        const int b = row0 >> 8, n = row0 & 255;
        ushort4v o;
        #pragma unroll
        for (int r = 0; r < 4; r++) o[r] = f2b(a[r]);
        *(ushort4v*)((unsigned short*)Cv + (long long)b * 65536 + col * 256 + n) = o;
      } else if (mode == 8) {
        float* Cf = (float*)Cv;
        const float* attf = (const float*)aux2;
        const float bv = aux1[col];
        #pragma unroll
        for (int r = 0; r < 4; r++) {
          const long long idx = (long long)(row0 + r) * 256 + col;
          Cf[idx] = gcn[idx] + attf[idx] + (a[r] + bv) * mask[row0 + r];
        }
      } else if (mode == 9) {
        const int token = zb * 256 + col;
        const float m = mask[token];
        ushort4v o; floatx4 g;
        #pragma unroll
        for (int r = 0; r < 4; r++) {
          const float v = fmaxf((a[r] + aux1[row0 + r]) * m, 0.f);
          o[r] = f2b(v); g[r] = v;
        }
        *(ushort4v*)((unsigned short*)Cv + (long long)token * 256 + row0) = o;
        float* gp = gcn + (long long)token * 256 + row0;
        if (flag) { floatx4 old = *(const floatx4*)gp; g += old; }
        *(floatx4*)gp = g;
      } else if (mode == 12) { // U = GCN + (val + bo)*mask
        float* Cf = (float*)Cv;
        const float bv = aux1[col];
        #pragma unroll
        for (int r = 0; r < 4; r++) {
          const long long idx = (long long)(row0 + r) * 256 + col;
          Cf[idx] = gcn[idx] + (a[r] + bv) * mask[row0 + r];
        }
      } else if (mode == 13) { // scaled bf16 (ABH /16)
        unsigned short* Cb = (unsigned short*)Cv;
        #pragma unroll
        for (int r = 0; r < 4; r++)
          Cb[cbase + (long long)(row0 + r) * ldc + col] = f2b(a[r] * 0.0625f);
      } else { // 16: V^T scatter only (col = h*256 + e)
        const int z2 = (row0 >> 8) * 8 + (col >> 8);
        const int e = col & 255, n = row0 & 255;
        ushort4v o;
        #pragma unroll
        for (int r = 0; r < 4; r++) o[r] = f2b(a[r]);
        *(ushort4v*)((unsigned short*)aux2 + (long long)z2 * 65536 + e * 256 + n) = o;
      }
    }
  }
}

// ---------------------------------------------------------------------------
// Fused attention v12 (= v11 + 3-buffer single-barrier rotation):
//  * v11 diagnosis: FETCH dropped to ~unique (55 MB) but time barely moved ->
//    stall is structural: ~54 barriers/block (2/iter + vmcnt sequencing) on
//    ~200-400cy compute phases, plus the LDS-read floor.
//  * v12: 3 stream buffers (c%3), ONE barrier per iteration:
//      [VMW2; MBAR; compute(c); STAGE(c+2)]
//    Race-free: a fast wave cannot reach STAGE(c+3) (overwriting buf c%3)
//    without passing iter c+1's MBAR, which gates on every slow wave
//    finishing compute(c).  VMW2 at iter c waits on chunk c staged TWO
//    iterations earlier -> lookahead doubles.  Barriers 54 -> 30.
//  * LDS budget kept at 80 KB (2 blocks/CU): sR0 shrunk to 32 KB (epilogue
//    reuses the XOR-swizzled layout instead of stride-264), redm/reds (2 KB)
//    carved into stream-buf 0 — provably dead there during softmax (holds
//    consumed chunk 15; chunk 18 lands only after reductions are consumed).
//  * Whole-b XCD grouping, continuous ledger, Q'-fusion: unchanged from v11.
// ---------------------------------------------------------------------------
__launch_bounds__(512, 4)
__global__ void attn_kernel(unsigned short* __restrict__ QP,   // (16384,2048) Y out
                            const unsigned short* __restrict__ HBF, // (16384,256)
                            const unsigned short* __restrict__ ABH, // (2048,256)
                            const unsigned short* __restrict__ VT,  // (512,256,256)
                            const unsigned short* __restrict__ DSTB,// (64,256,256) bf16
                            const float* __restrict__ mask)
{
  __shared__ __align__(16) unsigned short sR0[16384];  // 32KB: Hq -> Q' -> P -> Yepi
  __shared__ __align__(16) unsigned short sS[24576];   // 48KB: 3 x 16KB stream bufs

  // whole-b XCD grouping (v11): XCD x owns b in {x, x+8, ..., x+56};
  // within b, mt fastest, then h.
  const int bi = blockIdx.x;              // 0..2047
  const int x  = bi & 7;
  const int seq = bi >> 3;                // 0..255 within XCD
  const int b  = (seq >> 5) * 8 + x;      // 8 b's per XCD
  const int h  = (seq >> 2) & 7;
  const int mt = seq & 3;
  const int m0 = mt * 64;
  const int z = b * 8 + h;

  const int t = threadIdx.x, lane = t & 63, w = t >> 6;
  const int lm = lane & 15, qd = lane >> 4;
  const int wm2 = w >> 2, wn4 = w & 3;    // 2 row-groups x 4 key/e-groups

  unsigned short* Ym = QP + ((long long)(b * 256 + m0)) * 2048 + h * 256;
  const unsigned short* Hb = HBF + (long long)b * 65536;
  const unsigned short* Hq = Hb + (long long)m0 * 256;
  const unsigned short* Ah = ABH + (long long)h * 65536;
  const unsigned short* Vb = VT + (long long)z * 65536;
  const unsigned short* db = DSTB + (long long)b * 65536 + (long long)m0 * 256;
  const float* maskb = mask + b * 256;

  // redm/reds alias into stream-buf 0 (valid ONLY during softmax):
  // redm = redf[0..255], reds = redf[256..511]
  float* redf = (float*)sS;

  // ---- dist preload (compiler waits before use; S-phase MFMA C-in) ----
  floatx4 S[2][4];
  #pragma unroll
  for (int mi = 0; mi < 2; mi++)
    #pragma unroll
    for (int ni = 0; ni < 4; ni++) {
      const int col = wn4 * 64 + ni * 16 + lm;
      #pragma unroll
      for (int r = 0; r < 4; r++) {
        const int row = wm2 * 32 + mi * 16 + qd * 4 + r;
        S[mi][ni][r] = b2f(db[row * 256 + col]);
      }
    }

  // ---- per-thread staging geometry (all 24 chunks: 256 rows x 64 B) ----
  int eoff0, eoff1;
  {
    const int rA = lane >> 2, sl = lane & 3;
    const int r0 = (w * 2 + 0) * 16 + rA;
    const int r1 = (w * 2 + 1) * 16 + rA;
    eoff0 = r0 * 256 + ((sl ^ ((r0 >> 1) & 3)) * 8);
    eoff1 = r1 * 256 + ((sl ^ ((r1 >> 1) & 3)) * 8);
  }
  const int ld0 = (w * 2 + 0) * 512;
  const int ld1 = (w * 2 + 1) * 512;

  auto STAGE = [&](int c) {
    const unsigned short* bp =
        (c < 8 ? Ah : (c < 16 ? Hb : Vb)) + (c & 7) * 32;
    const int bb = (c % 3) * 8192;       // 3-buffer rotation
    gl_lds16(bp + eoff0, &sS[bb + ld0], lane);
    gl_lds16(bp + eoff1, &sS[bb + ld1], lane);
  };

  // ---- prologue: H_q tile (32 KB -> sR0) + chunks 0,1 ----
  {
    const int rin2 = lane >> 5, qs32 = lane & 31;
    #pragma unroll
    for (int i = 0; i < 4; i++) {
      const int d = w * 4 + i;
      const int r = d * 2 + rin2;          // H_q row 0..63
      gl_lds16(Hq + (long long)r * 256 + ((qs32 ^ (r & 7)) * 8),
               &sR0[d * 512], lane);
    }
  }
  STAGE(0); STAGE(1);                      // outstanding: Hq(4) + c0(2) + c1(2)

  // ---- phase 1: Q' = H_q * ABH_h^T  (chunks 0..7) ----
  floatx4 accq[2][4] = {};
  #pragma unroll
  for (int c = 0; c < 8; c++) {
    VMW2();                                // retires (Hq+)chunk c
    MBAR();                                // all waves certified chunk c
    __builtin_amdgcn_s_setprio(1);
    short8 af[2], bg[4];
    #pragma unroll
    for (int mi = 0; mi < 2; mi++) {
      const int r = wm2 * 32 + mi * 16 + lm;
      const int q = c * 4 + qd;
      af[mi] = *(const short8*)&sR0[r * 256 + ((q ^ (r & 7)) * 8)];
    }
    const int bb = (c % 3) * 8192;
    #pragma unroll
    for (int ni = 0; ni < 4; ni++) {
      const int rr = wn4 * 64 + ni * 16 + lm;
      bg[ni] = *(const short8*)&sS[bb + rr * 32 + ((qd ^ ((rr >> 1) & 3)) * 8)];
    }
    #pragma unroll
    for (int mi = 0; mi < 2; mi++)
      #pragma unroll
      for (int ni = 0; ni < 4; ni++)
        accq[mi][ni] = __builtin_amdgcn_mfma_f32_16x16x32_bf16(
            af[mi], bg[ni], accq[mi][ni], 0, 0, 0);
    __builtin_amdgcn_s_setprio(0);
    STAGE(c + 2);                          // chunks 2..9
  }

  // ---- transition: H_q dead after this barrier; materialize Q' ----
  MBAR();
  #pragma unroll
  for (int mi = 0; mi < 2; mi++)
    #pragma unroll
    for (int rr = 0; rr < 4; rr++) {
      const int row = wm2 * 32 + mi * 16 + qd * 4 + rr;
      #pragma unroll
      for (int ni = 0; ni < 4; ni++) {
        const int col = wn4 * 64 + ni * 16 + lm;
        const int o = col >> 3;
        sR0[row * 256 + ((o ^ (row & 7)) * 8) + (col & 7)] = f2b(accq[mi][ni][rr]);
      }
    }
  LGW0();                                  // iter-8 MBAR makes Q' visible

  // ---- phase 2: S = Q' * H^T + dist  (chunks 8..15) ----
  #pragma unroll
  for (int c = 8; c < 16; c++) {
    VMW2();
    MBAR();
    __builtin_amdgcn_s_setprio(1);
    short8 af[2], bg[4];
    #pragma unroll
    for (int mi = 0; mi < 2; mi++) {
      const int r = wm2 * 32 + mi * 16 + lm;
      const int q = (c - 8) * 4 + qd;
      af[mi] = *(const short8*)&sR0[r * 256 + ((q ^ (r & 7)) * 8)];
    }
    const int bb = (c % 3) * 8192;
    #pragma unroll
    for (int ni = 0; ni < 4; ni++) {
      const int rr = wn4 * 64 + ni * 16 + lm;
      bg[ni] = *(const short8*)&sS[bb + rr * 32 + ((qd ^ ((rr >> 1) & 3)) * 8)];
    }
    #pragma unroll
    for (int mi = 0; mi < 2; mi++)
      #pragma unroll
      for (int ni = 0; ni < 4; ni++)
        S[mi][ni] = __builtin_amdgcn_mfma_f32_16x16x32_bf16(
            af[mi], bg[ni], S[mi][ni], 0, 0, 0);
    __builtin_amdgcn_s_setprio(0);
    STAGE(c + 2);                          // chunks 10..17
  }

  // ---- softmax (redm/reds live in dead stream-buf 0 = chunk 15) ----
  MBAR();                                  // chunk-15 region free; Q' still live
  float mkv[4];
  #pragma unroll
  for (int ni = 0; ni < 4; ni++) mkv[ni] = maskb[wn4 * 64 + ni * 16 + lm];

  float lred[2][4];
  #pragma unroll
  for (int mi = 0; mi < 2; mi++) {
    #pragma unroll
    for (int r = 0; r < 4; r++) {
      const int row = wm2 * 32 + mi * 16 + qd * 4 + r;
      const float mq = maskb[m0 + row];
      float mx = -3e38f;
      #pragma unroll
      for (int ni = 0; ni < 4; ni++) {
        const float v = (mq != 0.f && mkv[ni] != 0.f) ? S[mi][ni][r] : -1e9f;
        S[mi][ni][r] = v;
        mx = fmaxf(mx, v);
      }
      lred[mi][r] = mx;
    }
  }
  #pragma unroll
  for (int off = 1; off < 16; off <<= 1)
    #pragma unroll
    for (int mi = 0; mi < 2; mi++)
      #pragma unroll
      for (int r = 0; r < 4; r++)
        lred[mi][r] = fmaxf(lred[mi][r], __shfl_xor(lred[mi][r], off));
  if (lm == 0)
    #pragma unroll
    for (int mi = 0; mi < 2; mi++)
      #pragma unroll
      for (int r = 0; r < 4; r++)
        redf[wn4 * 64 + wm2 * 32 + mi * 16 + qd * 4 + r] = lred[mi][r];
  LGW0();
  MBAR();

  #pragma unroll
  for (int mi = 0; mi < 2; mi++) {
    #pragma unroll
    for (int r = 0; r < 4; r++) {
      const int row = wm2 * 32 + mi * 16 + qd * 4 + r;
      const float gmax = fmaxf(fmaxf(redf[row], redf[64 + row]),
                               fmaxf(redf[128 + row], redf[192 + row]));
      float ss = 0.f;
      #pragma unroll
      for (int ni = 0; ni < 4; ni++) {
        const float e = __expf(S[mi][ni][r] - gmax);   // invalid -> exactly 0
        S[mi][ni][r] = e;
        ss += e;
      }
      lred[mi][r] = ss;
    }
  }
  #pragma unroll
  for (int off = 1; off < 16; off <<= 1)
    #pragma unroll
    for (int mi = 0; mi < 2; mi++)
      #pragma unroll
      for (int r = 0; r < 4; r++)
        lred[mi][r] += __shfl_xor(lred[mi][r], off);
  if (lm == 0)
    #pragma unroll
    for (int mi = 0; mi < 2; mi++)
      #pragma unroll
      for (int r = 0; r < 4; r++)
        redf[256 + wn4 * 64 + wm2 * 32 + mi * 16 + qd * 4 + r] = lred[mi][r];
  LGW0();
  MBAR();

  // normalize; P planes [wn4][64 rows][64 keys] into sR0 (overwrites Q')
  #pragma unroll
  for (int mi = 0; mi < 2; mi++)
    #pragma unroll
    for (int r = 0; r < 4; r++) {
      const int row = wm2 * 32 + mi * 16 + qd * 4 + r;
      const float inv = 1.0f / (redf[256 + row] + redf[320 + row] +
                                redf[384 + row] + redf[448 + row]);
      #pragma unroll
      for (int ni = 0; ni < 4; ni++) {
        const int kl = ni * 16 + lm;
        const int slot = (kl >> 3) ^ (row & 7);
        sR0[wn4 * 4096 + row * 64 + slot * 8 + (kl & 7)] =
            f2b(S[mi][ni][r] * inv);
      }
    }
  LGW0();                                  // iter-16 MBAR makes P visible

  // ---- phase 3: Y = P * V  (chunks 16..23) ----
  floatx4 Y[2][4] = {};
  #pragma unroll
  for (int c = 16; c < 24; c++) {
    if (c < 23) { VMW2(); } else { VMW0(); }
    MBAR();
    __builtin_amdgcn_s_setprio(1);
    const int pp = (c - 16) >> 1;
    const int op = ((c - 16) & 1) * 4 + qd;
    short8 af[2], bg[4];
    #pragma unroll
    for (int mi = 0; mi < 2; mi++) {
      const int r = wm2 * 32 + mi * 16 + lm;
      af[mi] = *(const short8*)&sR0[pp * 4096 + r * 64 + ((op ^ (r & 7)) * 8)];
    }
    const int bb = (c % 3) * 8192;
    #pragma unroll
    for (int ni = 0; ni < 4; ni++) {
      const int rr = wn4 * 64 + ni * 16 + lm;
      bg[ni] = *(const short8*)&sS[bb + rr * 32 + ((qd ^ ((rr >> 1) & 3)) * 8)];
    }
    #pragma unroll
    for (int mi = 0; mi < 2; mi++)
      #pragma unroll
      for (int ni = 0; ni < 4; ni++)
        Y[mi][ni] = __builtin_amdgcn_mfma_f32_16x16x32_bf16(
            af[mi], bg[ni], Y[mi][ni], 0, 0, 0);
    __builtin_amdgcn_s_setprio(0);
    if (c < 22) STAGE(c + 2);              // chunks 18..23
  }

  // ---- epilogue: Y -> sR0 (XOR-swizzled, reuses P space) -> 16B stores ----
  MBAR();                                  // all waves done with P
  #pragma unroll
  for (int mi = 0; mi < 2; mi++)
    #pragma unroll
    for (int ni = 0; ni < 4; ni++) {
      const int col = wn4 * 64 + ni * 16 + lm;
      #pragma unroll
      for (int r = 0; r < 4; r++) {
        const int row = wm2 * 32 + mi * 16 + qd * 4 + r;
        sR0[row * 256 + (((col >> 3) ^ (row & 7)) * 8) + (col & 7)] =
            f2b(Y[mi][ni][r]);
      }
    }
  LGW0();
  MBAR();
  #pragma unroll
  for (int it = 0; it < 4; it++) {
    const int idx = it * 512 + t;          // 0..2047 = 64 rows x 32 x 16B
    const int row = idx >> 5, u = idx & 31;
    short8 v = *(const short8*)&sR0[row * 256 + ((u ^ (row & 7)) * 8)];
    *(short8*)(Ym + (long long)row * 2048 + u * 8) = v;
  }
}

// ---------------------------------------------------------------------------
__global__ void ln_kernel(const float* __restrict__ X,
                          const float* __restrict__ gam,
                          const float* __restrict__ bet,
                          unsigned short* __restrict__ out)
{
  const int g = blockIdx.x * 4 + (threadIdx.x >> 6);
  const int lane = threadIdx.x & 63;
  floatx4 v = *(const floatx4*)(X + (long long)g * 256 + lane * 4);
  float s = v[0] + v[1] + v[2] + v[3];
  float sq = v[0]*v[0] + v[1]*v[1] + v[2]*v[2] + v[3]*v[3];
  #pragma unroll
  for (int off = 32; off > 0; off >>= 1) {
    s  += __shfl_xor(s, off);
    sq += __shfl_xor(sq, off);
  }
  const float mean = s * (1.0f / 256.0f);
  const float var = sq * (1.0f / 256.0f) - mean * mean;
  const float rs = 1.0f / sqrtf(var + 1e-5f);
  ushort4v o;
  #pragma unroll
  for (int jj = 0; jj < 4; jj++) {
    const int c = lane * 4 + jj;
    o[jj] = f2b((v[jj] - mean) * rs * gam[c] + bet[c]);
  }
  *(ushort4v*)(out + (long long)g * 256 + lane * 4) = o;
}

// ---------------------------------------------------------------------------
static inline void launch_gemm(hipStream_t st, int M, int N, int batch,
    const void* A, int lda, long long sAo, long long sAi,
    const void* B, int ldb, long long sBo, long long sBi,
    void* C, int ldc, long long sCo, long long sCi,
    int K, int zshift, int mode, int flag,
    const float* aux1, const float* mask, float* gcn, void* aux2)
{
  dim3 grid(M / 128, N / 128, batch), blk(512);
  gemm_kernel<<<grid, blk, 0, st>>>(
      (const unsigned short*)A, lda, sAo, sAi,
      (const unsigned short*)B, ldb, sBo, sBi,
      C, ldc, sCo, sCi, K, zshift, mode, flag, aux1, mask, gcn, aux2);
}

extern "C" void kernel_launch(void* const* d_in, const int* in_sizes, int n_in,
                              void* d_out, int out_size, void* d_ws, size_t ws_size,
                              hipStream_t stream)
{
  (void)in_sizes; (void)n_in; (void)out_size;
  const float* x    = (const float*)d_in[0];
  const float* adj  = (const float*)d_in[1];
  const float* mask = (const float*)d_in[2];
  const float* dist = (const float*)d_in[3];
  const float* W1   = (const float*)d_in[4];
  const float* b1   = (const float*)d_in[5];
  const float* W2   = (const float*)d_in[6];
  const float* b2   = (const float*)d_in[7];
  const float* W3   = (const float*)d_in[8];
  const float* b3   = (const float*)d_in[9];
  const float* ln1g = (const float*)d_in[10];
  const float* ln1b = (const float*)d_in[11];
  const float* Wq   = (const float*)d_in[12];
  const float* Wk   = (const float*)d_in[13];
  const float* Wv   = (const float*)d_in[14];
  const float* Wo   = (const float*)d_in[15];
  const float* bo   = (const float*)d_in[16];
  const float* ln2g = (const float*)d_in[17];
  const float* ln2b = (const float*)d_in[18];
  const float* Wf1  = (const float*)d_in[19];
  const float* bf1  = (const float*)d_in[20];
  const float* Wf2  = (const float*)d_in[21];
  const float* bf2  = (const float*)d_in[22];

  char* w = (char*)d_ws;
  auto alloc = [&](size_t sz) { void* p = (void*)w; w += sz; return p; };
  // persistent (~61 MB)
  unsigned short* W1T   = (unsigned short*)alloc(65536);      // (256,128)
  unsigned short* W2T   = (unsigned short*)alloc(131072);     // (256,256)
  unsigned short* W3T   = (unsigned short*)alloc(131072);
  unsigned short* ABH   = (unsigned short*)alloc(1048576);    // (2048,256) = Wk_h Wq_h^T /16
  unsigned short* WVT   = (unsigned short*)alloc(1048576);    // (2048,256)
  unsigned short* WOT   = (unsigned short*)alloc(1048576);    // (256,2048)
  unsigned short* WF1T  = (unsigned short*)alloc(524288);     // (1024,256)
  unsigned short* WF2T  = (unsigned short*)alloc(524288);     // (256,1024)
  unsigned short* WQb   = (unsigned short*)alloc(1048576);    // (256,2048) plain
  unsigned short* WKb   = (unsigned short*)alloc(1048576);    // (256,2048) plain
  unsigned short* XBF   = (unsigned short*)alloc(4194304);    // (16384,128)
  unsigned short* DSTB  = (unsigned short*)alloc(8388608);    // (64,256,256) bf16 dist
  float*          GCN   = (float*)         alloc(16777216);   // (16384,256)
  float*          U     = (float*)         alloc(16777216);   // ATT f32
  unsigned short* HBF   = (unsigned short*)alloc(8388608);    // (16384,256)
  float*          DIS   = (float*)         alloc(65536);
  // scratch union (peak = attention: 134.2 MB)
  char* scratch = (char*)alloc(134217728);
  if ((size_t)(w - (char*)d_ws) > ws_size) return;
  // gcn phase views
  unsigned short* AN  = (unsigned short*)scratch;              // 8.4 MB
  unsigned short* TT  = (unsigned short*)(scratch + 8388608);  // 8.4 MB
  unsigned short* GBF = (unsigned short*)(scratch + 16777216); // 8.4 MB
  // attention phase views
  unsigned short* QPB = (unsigned short*)scratch;                 // (16384,2048) 67 MB  Y
  unsigned short* VT  = (unsigned short*)(scratch + 67108864);    // (512,256,256) 67 MB
  // ffn phase view
  unsigned short* FFB = (unsigned short*)scratch;                 // 33.6 MB

  // ---- single packing launch: 7 transposes + 4 plain cvts ----
  PackArgs pa;
  const float* srcs[11] = {W1, W2, W3, Wv, Wo, Wf1, Wf2, x, Wq, Wk, dist};
  unsigned short* dsts[11] = {W1T, W2T, W3T, WVT, WOT, WF1T, WF2T, XBF, WQb, WKb, DSTB};
  const int Rs[11] = {128, 256, 256, 256, 2048, 256, 1024,
                      BNROWS * INF_, EE * HH * EE, EE * HH * EE, BB * 65536};
  const int Cs[11] = {256, 256, 256, 2048, 256, 1024, 256, 0, 0, 0, 0};
  const int sts[12] = {0, 32, 96, 160, 672, 1184, 1440, 1696, 3744, 4256, 4768, 8864};
  for (int j = 0; j < 11; j++) {
    pa.src[j] = srcs[j]; pa.dst[j] = dsts[j]; pa.R[j] = Rs[j]; pa.C[j] = Cs[j];
  }
  for (int j = 0; j < 12; j++) pa.start[j] = sts[j];
  pack_kernel<<<8864, 256, 0, stream>>>(pa);

  // ---- adjacency normalization ----
  deg_kernel<<<4096, 256, 0, stream>>>(adj, DIS);
  an_kernel<<<4096, 256, 0, stream>>>(adj, DIS, AN);

  // ---- ABH_h = Wk_h Wq_h^T / 16  (8 heads, tiny batched GEMM) ----
  launch_gemm(stream, 256, 256, 8, WKb, 2048, 256, 0, WQb, 2048, 256, 0,
              ABH, 256, 65536, 0, 256, 0, 13, 0, nullptr, nullptr, nullptr, nullptr);

  // ---- GCN stack ----
  launch_gemm(stream, BNROWS, EE, 1, XBF, 128, 0,0, W1T, 128, 0,0,
              TT, 256, 0,0, 128, 0, 5, 0, nullptr, nullptr, nullptr, nullptr);
  launch_gemm(stream, 256, 256, BB, TT, 256, 65536,0, AN, 256, 65536,0,
              GBF, 256, 0,0, 256, 0, 9, 0, b1, mask, GCN, nullptr);
  launch_gemm(stream, BNROWS, EE, 1, GBF, 256, 0,0, W2T, 256, 0,0,
              TT, 256, 0,0, 256, 0, 5, 0, nullptr, nullptr, nullptr, nullptr);
  launch_gemm(stream, 256, 256, BB, TT, 256, 65536,0, AN, 256, 65536,0,
              GBF, 256, 0,0, 256, 0, 9, 1, b2, mask, GCN, nullptr);
  launch_gemm(stream, BNROWS, EE, 1, GBF, 256, 0,0, W3T, 256, 0,0,
              TT, 256, 0,0, 256, 0, 5, 0, nullptr, nullptr, nullptr, nullptr);
  launch_gemm(stream, 256, 256, BB, TT, 256, 65536,0, AN, 256, 65536,0,
              GBF, 256, 0,0, 256, 0, 9, 1, b3, mask, GCN, nullptr);

  // ---- LN1 ----
  ln_kernel<<<4096, 256, 0, stream>>>(GCN, ln1g, ln1b, HBF);

  // ---- attention: V^T GEMM -> fused attn (Q' in-kernel) -> Y@Wo ----
  launch_gemm(stream, BNROWS, 2048, 1, HBF, 256, 0,0, WVT, 256, 0,0,
              QPB, 2048, 0,0, 256, 0, 16, 0, nullptr, nullptr, nullptr, VT);
  attn_kernel<<<2048, 512, 0, stream>>>(QPB, HBF, ABH, VT, DSTB, mask);
  launch_gemm(stream, BNROWS, EE, 1, QPB, 2048, 0,0, WOT, 2048, 0,0,
              U, 256, 0,0, 2048, 0, 12, 0, bo, mask, GCN, nullptr);

  // ---- LN2 + FFN (final residual fused into FFN2 epilogue) ----
  ln_kernel<<<4096, 256, 0, stream>>>(U, ln2g, ln2b, HBF);
  launch_gemm(stream, BNROWS, FFN, 1, HBF, 256, 0,0, WF1T, 256, 0,0,
              FFB, 1024, 0,0, 256, 0, 3, 0, bf1, nullptr, nullptr, nullptr);
  launch_gemm(stream, BNROWS, EE, 1, FFB, 1024, 0,0, WF2T, 1024, 0,0,
              d_out, 256, 0,0, 1024, 0, 8, 0, bf2, mask, GCN, U);
}